// Round 12
// baseline (197.178 us; speedup 1.0000x reference)
//
#include <hip/hip_runtime.h>

#define DEV static __device__ __forceinline__

typedef __bf16 bf16x8 __attribute__((ext_vector_type(8)));
typedef float f32x4 __attribute__((ext_vector_type(4)));
typedef unsigned short u16x8 __attribute__((ext_vector_type(8)));
typedef unsigned short u16x4 __attribute__((ext_vector_type(4)));
typedef unsigned int u32x2 __attribute__((ext_vector_type(2)));

constexpr int Bv = 4, Lv = 2048, Dv = 1024, Hv = 8;
constexpr int BL = Bv * Lv;   // 8192
constexpr int CH = 64;        // chunk length
constexpr int NC = Lv / CH;   // 32 chunks

DEV float bf2f(unsigned short u) {
  union { unsigned int i; float f; } c; c.i = ((unsigned int)u) << 16; return c.f;
}
DEV unsigned short f2bf(float f) {  // RNE
  union { float f; unsigned int i; } c; c.f = f;
  unsigned int x = c.i;
  unsigned int r = (x >> 16) & 1u;
  x += 0x7fffu + r;
  return (unsigned short)(x >> 16);
}

// packed f32x2 -> bf16x2 (low = a, high = b); no builtin on gfx950 -> asm (T12)
DEV unsigned int cvtpk(float a, float b) {
  unsigned int r;
  asm("v_cvt_pk_bf16_f32 %0, %1, %2" : "=v"(r) : "v"(a), "v"(b));
  return r;
}
DEV float frcp(float x) { float r; asm("v_rcp_f32 %0, %1" : "=v"(r) : "v"(x)); return r; }

// K=16 bf16 MFMA via asm. s_nop 1 guards VALU-write -> MFMA-read hazard.
DEV f32x4 mfma16(u32x2 a, u32x2 b, f32x4 c) {
  asm("s_nop 1\n\tv_mfma_f32_16x16x16_bf16 %0, %1, %2, %0" : "+v"(c) : "v"(a), "v"(b));
  return c;
}
DEV void mfma_fence() { asm volatile("s_nop 7\n\ts_nop 7"); }  // MFMA D -> VALU read

// ---------------- fused prep: LN rows (bid<8192) + weight cvt (bid>=8192) ---------------
__global__ __launch_bounds__(256) void prep_kernel(
    const float* __restrict__ x, const float* __restrict__ gamma,
    const float* __restrict__ beta, unsigned short* __restrict__ xnb,
    const float* __restrict__ Wq, const float* __restrict__ Wk,
    const float* __restrict__ Wv, const float* __restrict__ Wg,
    const float* __restrict__ Wo,
    unsigned short* __restrict__ Wcat, unsigned short* __restrict__ Wob) {
  const int bid = blockIdx.x, tid = threadIdx.x;
  if (bid < 8192) {
    const int row = bid;
    const float4 v = ((const float4*)(x + (size_t)row * 1024))[tid];
    float s = v.x + v.y + v.z + v.w;
    float q = v.x * v.x + v.y * v.y + v.z * v.z + v.w * v.w;
#pragma unroll
    for (int m = 1; m <= 32; m <<= 1) { s += __shfl_xor(s, m, 64); q += __shfl_xor(q, m, 64); }
    __shared__ float red[8];
    const int wave = tid >> 6, lane = tid & 63;
    if (lane == 0) { red[wave] = s; red[wave + 4] = q; }
    __syncthreads();
    s = red[0] + red[1] + red[2] + red[3];
    q = red[4] + red[5] + red[6] + red[7];
    const float mu = s * (1.0f / 1024.0f);
    const float var = q * (1.0f / 1024.0f) - mu * mu;
    const float rstd = rsqrtf(var + 1e-5f);
    const float4 g4 = ((const float4*)gamma)[tid];
    const float4 b4 = ((const float4*)beta)[tid];
    u16x4 o;
    o[0] = f2bf((v.x - mu) * rstd * g4.x + b4.x);
    o[1] = f2bf((v.y - mu) * rstd * g4.y + b4.y);
    o[2] = f2bf((v.z - mu) * rstd * g4.z + b4.z);
    o[3] = f2bf((v.w - mu) * rstd * g4.w + b4.w);
    ((u16x4*)(xnb + (size_t)row * 1024))[tid] = o;
  } else {
    const int i = (bid - 8192) * 256 + tid;
    const int NW4 = (4 * 1024 * 1024) / 4;
    const float* src; unsigned short* dst;
    if (i < NW4) {
      const int e0 = i * 4;
      const int which = e0 >> 20;
      const int off = e0 & ((1 << 20) - 1);
      src = (which == 0 ? Wq : which == 1 ? Wk : which == 2 ? Wv : Wg) + off;
      dst = Wcat + e0;
    } else {
      const int e0 = (i - NW4) * 4;
      src = Wo + e0;
      dst = Wob + e0;
    }
    const float4 v = *(const float4*)src;
    u16x4 o;
    o[0] = f2bf(v.x); o[1] = f2bf(v.y); o[2] = f2bf(v.z); o[3] = f2bf(v.w);
    *(u16x4*)dst = o;
  }
}

DEV void gld16(const void* g, void* l) {
  __builtin_amdgcn_global_load_lds((const __attribute__((address_space(1))) void*)g,
                                   (__attribute__((address_space(3))) void*)l, 16, 0, 0);
}

// ---------------- gemm256: 256xBN tile, BK=32, 4-slot ring, fine phases + counted vmcnt -
// A[M][1024], Bt[N][1024] bf16 -> C[M][NCOLS]; sigmoid epilogue on cols >= 3072 if GATE.
// LDS ring: 4 slots x (A 256x32 + B BNx32) bf16, rows of 64B; chunk c (16B) of row r
// stored at c ^ ((r>>1)&3) -> b128 frag reads are 2 lanes/bank (free). Staging = linear
// gld16 dest + pre-swizzled global source (rule 21).
// Per K-tile: 2 quadrant-phases of {ds_read frags | stage 1 half-tile for kt+3 ->
// barrier -> setprio(1) 16 MFMA setprio(0) -> barrier}; boundary wait = counted
// vmcnt(2*LPT) BEFORE the closing barrier (never drains; tiles kt+2,kt+3 stay in
// flight; per-wave count + barrier = collective guarantee; ring distance 3 => stage
// target never aliases the slot being read).
template <typename OUT_T, int BN, int NCOLS, bool GATE>
__global__ __launch_bounds__(512, 2) void gemm256(
    const unsigned short* __restrict__ A, const unsigned short* __restrict__ Bt,
    OUT_T* __restrict__ C) {
  constexpr int JW = BN / 64;             // j-frags per wave (4 or 2)
  constexpr int TN = NCOLS / BN;          // n tiles
  constexpr int KT = 32;                  // K = 1024 = 32 * 32
  constexpr int ABUF = 256 * 32;          // shorts per A slot (16 KB)
  constexpr int BBUF = BN * 32;           // shorts per B slot
  constexpr int BUFS = ABUF + BBUF;       // shorts per ring slot
  constexpr int LPT = 2 + BN / 128;       // gld16 per thread per K-tile (4 or 3)
  extern __shared__ __align__(16) unsigned short lds[];
  int bid = blockIdx.x;
  const int cpx = gridDim.x >> 3;
  bid = (bid & 7) * cpx + (bid >> 3);     // XCD swizzle (grid % 8 == 0)
  const int tm = bid / TN, tn = bid % TN;
  const int gm = tm << 8, gn = tn * BN;
  const int tid = threadIdx.x, w = tid >> 6, l = tid & 63;
  const int wm = w >> 2, wn = w & 3;
  const int fr = l & 15, q = l >> 4;
  // stage mapping: one gld16 call covers 128 rows x 64B; thread -> (row, chunkpos)
  const int srow = tid >> 2;                       // 0..127
  const int schk = (tid & 3) ^ ((srow >> 1) & 3);  // pre-swizzled source chunk
  const char* ldsc = (const char*)lds;

  f32x4 acc[8][JW] = {};

  const unsigned short* Abase = A + (size_t)(gm + srow) * 1024 + schk * 8;
  const unsigned short* Bbase = Bt + (size_t)(gn + srow) * 1024 + schk * 8;

  auto STAGE_A = [&](int slot, int kt) {
#pragma unroll
    for (int c = 0; c < 2; ++c)
      gld16(Abase + (size_t)(c * 128) * 1024 + kt * 32,
            &lds[slot * BUFS + c * 4096 + w * 512]);
  };
  auto STAGE_B = [&](int slot, int kt) {
#pragma unroll
    for (int c = 0; c < BN / 128; ++c)
      gld16(Bbase + (size_t)(c * 128) * 1024 + kt * 32,
            &lds[slot * BUFS + ABUF + c * 4096 + w * 512]);
  };
  auto RDA = [&](int slot, int i) -> bf16x8 {   // i = 0..7
    const int row = wm * 128 + i * 16 + fr;
    const int byte = row * 64 + ((q << 4) ^ (((row >> 1) & 3) << 4));
    return *(const bf16x8*)(ldsc + slot * (BUFS * 2) + byte);
  };
  auto RDB = [&](int slot, int j) -> bf16x8 {   // j = 0..JW-1
    const int row = wn * (JW * 16) + j * 16 + fr;
    const int byte = row * 64 + ((q << 4) ^ (((row >> 1) & 3) << 4));
    return *(const bf16x8*)(ldsc + slot * (BUFS * 2) + ABUF * 2 + byte);
  };

  // prologue: stage tiles 0,1,2; wait until tile 0 landed (counted)
#pragma unroll
  for (int kt = 0; kt < 3; ++kt) { STAGE_A(kt, kt); STAGE_B(kt, kt); }
  if constexpr (LPT == 4) asm volatile("s_waitcnt vmcnt(8)" ::: "memory");
  else                    asm volatile("s_waitcnt vmcnt(6)" ::: "memory");
  __builtin_amdgcn_s_barrier();

#pragma unroll 4
  for (int kt = 0; kt < KT; ++kt) {
    const int slot = kt & 3;
    const int slot3 = (kt + 3) & 3;
    const bool st = (kt + 3 < KT);
    bf16x8 a[4], b[JW];
    // ---- phase 0: quadrant mq=0 ----
#pragma unroll
    for (int i = 0; i < 4; ++i) a[i] = RDA(slot, i);
#pragma unroll
    for (int j = 0; j < JW; ++j) b[j] = RDB(slot, j);
    if (st) STAGE_A(slot3, kt + 3);
    __builtin_amdgcn_s_barrier();
    __builtin_amdgcn_s_setprio(1);
#pragma unroll
    for (int i = 0; i < 4; ++i)
#pragma unroll
      for (int j = 0; j < JW; ++j)
        acc[i][j] = __builtin_amdgcn_mfma_f32_16x16x32_bf16(a[i], b[j], acc[i][j], 0, 0, 0);
    __builtin_amdgcn_s_setprio(0);
    __builtin_amdgcn_s_barrier();
    // ---- phase 1: quadrant mq=1 (B frags reused) ----
#pragma unroll
    for (int i = 0; i < 4; ++i) a[i] = RDA(slot, 4 + i);
    if (st) STAGE_B(slot3, kt + 3);
    __builtin_amdgcn_s_barrier();
    __builtin_amdgcn_s_setprio(1);
#pragma unroll
    for (int i = 0; i < 4; ++i)
#pragma unroll
      for (int j = 0; j < JW; ++j)
        acc[4 + i][j] = __builtin_amdgcn_mfma_f32_16x16x32_bf16(a[i], b[j], acc[4 + i][j], 0, 0, 0);
    __builtin_amdgcn_s_setprio(0);
    // ---- boundary: counted wait (kt+1's stages landed), then closing barrier ----
    if (kt < KT - 3) {
      if constexpr (LPT == 4) asm volatile("s_waitcnt vmcnt(8)" ::: "memory");
      else                    asm volatile("s_waitcnt vmcnt(6)" ::: "memory");
    } else if (kt == KT - 3) {
      if constexpr (LPT == 4) asm volatile("s_waitcnt vmcnt(4)" ::: "memory");
      else                    asm volatile("s_waitcnt vmcnt(3)" ::: "memory");
    } else if (kt == KT - 2) {
      asm volatile("s_waitcnt vmcnt(0)" ::: "memory");
    }
    if (kt < KT - 1) __builtin_amdgcn_s_barrier();
  }

  // epilogue: C row = m, col = n; optional sigmoid on gate cols
  const int er = q << 2, ec = fr;
#pragma unroll
  for (int i = 0; i < 8; ++i)
#pragma unroll
    for (int j = 0; j < JW; ++j)
#pragma unroll
      for (int r = 0; r < 4; ++r) {
        const int m = gm + wm * 128 + i * 16 + er + r;
        const int n = gn + wn * (JW * 16) + j * 16 + ec;
        float val = acc[i][j][r];
        if constexpr (GATE) { if (n >= 3072) val = 1.0f / (1.0f + __expf(-val)); }
        if constexpr (sizeof(OUT_T) == 2) ((unsigned short*)C)[(size_t)m * NCOLS + n] = f2bf(val);
        else                              C[(size_t)m * NCOLS + n] = val;
      }
}

// ---------------- Pass A: MFMA chunk kernel (CH=64, 4 sub-blocks of 16) -----------------
__global__ __launch_bounds__(256) void gla_chunk_mfma(
    const unsigned short* __restrict__ C1, unsigned short* __restrict__ ylocal,
    unsigned short* __restrict__ Qt, unsigned short* __restrict__ Mb,
    float* __restrict__ Dtot) {
  __shared__ unsigned short qs[16][136];   // q~  [t][k]
  __shared__ unsigned short ks[16][136];   // k~  [s][k]
  __shared__ unsigned short vt_[128][20];  // V^T [v][s]
  __shared__ unsigned short kh_[128][20];  // kh^T[k][s]
  __shared__ float lame[128];              // lam_end[k]

  const int bid = blockIdx.x;
  const int bh = bid >> 5, c = bid & 31;
  const int b = bh >> 3, h = bh & 7;
  const int tid = threadIdx.x, w = tid >> 6, l = tid & 63;
  const int tt = l & 15, sg = (l >> 4) << 2;
  const size_t row0 = (size_t)(b * Lv + c * CH);

  const float scale = 0.08838834764831845f;   // 128^-0.5
  const float inv_scale = 11.313708498984761f;

  f32x4 SA[8][2] = {};
  float chain = scale;

  for (int sb = 0; sb < 4; ++sb) {
    const size_t trow = row0 + sb * 16;
    if (tid < 128) {
      const int n = tid;
      const unsigned short* pc = C1 + trow * 4096 + h * 128 + n;
      float lam[16]; float lr = 1.f;
#pragma unroll
      for (int t = 0; t < 16; ++t) { lr *= bf2f(pc[(size_t)t * 4096 + 3072]); lam[t] = lr; }
      const float lend = lr;
      unsigned short khb[16];
#pragma unroll
      for (int t = 0; t < 16; ++t) {
        const float qv = bf2f(pc[(size_t)t * 4096]);
        const float kv = bf2f(pc[(size_t)t * 4096 + 1024]);
        const float qt = qv * lam[t];
        const float kt = kv * frcp(fmaxf(lam[t], 1e-30f));
        qs[t][n] = f2bf(qt);
        ks[t][n] = f2bf(kt);
        khb[t] = f2bf(kt * lend);
        Qt[(trow + t) * 1024 + h * 128 + n] = f2bf(qt * chain);
      }
#pragma unroll
      for (int s4 = 0; s4 < 16; s4 += 4)
        *(u16x4*)&kh_[n][s4] = *(u16x4*)&khb[s4];
      lame[n] = lend;
      chain *= lend;
    } else {
      const int i = tid - 128;
      const int s = i >> 3, vg = (i & 7) * 16;
      const unsigned short* pv = C1 + (trow + s) * 4096 + h * 128 + 2048 + vg;
      const u16x8 a0 = *(const u16x8*)pv;
      const u16x8 a1 = *(const u16x8*)(pv + 8);
#pragma unroll
      for (int e = 0; e < 8; ++e) { vt_[vg + e][s] = a0[e]; vt_[vg + 8 + e][s] = a1[e]; }
    }
    __syncthreads();

    f32x4 at = {};
#pragma unroll
    for (int k0 = 0; k0 < 128; k0 += 32) {
      const bf16x8 ka = *(const bf16x8*)&ks[tt][k0 + ((l >> 4) << 3)];
      const bf16x8 qa = *(const bf16x8*)&qs[tt][k0 + ((l >> 4) << 3)];
      at = __builtin_amdgcn_mfma_f32_16x16x32_bf16(ka, qa, at, 0, 0, 0);
    }
    float m0 = (sg + 0 <= tt) ? at[0] : 0.f;
    float m1 = (sg + 1 <= tt) ? at[1] : 0.f;
    float m2 = (sg + 2 <= tt) ? at[2] : 0.f;
    float m3 = (sg + 3 <= tt) ? at[3] : 0.f;
    u32x2 pf; pf[0] = cvtpk(m0, m1); pf[1] = cvtpk(m2, m3);

    u32x2 vf[2];
#pragma unroll
    for (int j = 0; j < 2; ++j)
      vf[j] = *(const u32x2*)&vt_[(w * 2 + j) * 16 + tt][sg];

    f32x4 OA[2] = {};
    if (sb) {
#pragma unroll
      for (int kt = 0; kt < 8; ++kt) {
        const u32x2 qf = *(const u32x2*)&qs[tt][kt * 16 + sg];
#pragma unroll
        for (int j = 0; j < 2; ++j) {
          u32x2 sa;
          sa[0] = cvtpk(SA[kt][j][0], SA[kt][j][1]);
          sa[1] = cvtpk(SA[kt][j][2], SA[kt][j][3]);
          OA[j] = mfma16(sa, qf, OA[j]);
        }
      }
    }
#pragma unroll
    for (int j = 0; j < 2; ++j) OA[j] = mfma16(vf[j], pf, OA[j]);
    mfma_fence();
#pragma unroll
    for (int j = 0; j < 2; ++j) {
      u16x4 yo;
#pragma unroll
      for (int r = 0; r < 4; ++r) yo[r] = f2bf(OA[j][r] * scale);
      *(u16x4*)&ylocal[(trow + tt) * 1024 + h * 128 + (w * 2 + j) * 16 + sg] = yo;
    }

#pragma unroll
    for (int kt = 0; kt < 8; ++kt) {
      const float4 lam4 = *(const float4*)&lame[kt * 16 + sg];
      const u32x2 khf = *(const u32x2*)&kh_[kt * 16 + tt][sg];
#pragma unroll
      for (int j = 0; j < 2; ++j) {
        f32x4 cs = SA[kt][j];
        cs[0] *= lam4.x; cs[1] *= lam4.y; cs[2] *= lam4.z; cs[3] *= lam4.w;
        SA[kt][j] = mfma16(khf, vf[j], cs);
      }
    }
    __syncthreads();
  }
  mfma_fence();

#pragma unroll
  for (int kt = 0; kt < 8; ++kt)
#pragma unroll
    for (int j = 0; j < 2; ++j)
#pragma unroll
      for (int r = 0; r < 4; ++r)
        Mb[((size_t)(bh * NC + c) * 128 + kt * 16 + sg + r) * 128 + (w * 2 + j) * 16 + tt] =
            f2bf(SA[kt][j][r]);
  if (tid < 128)
    Dtot[(bh * NC + c) * 128 + tid] = chain * inv_scale;
}

// ---------------- Pass B: serial chunk combine + transpose ------------------------------
__global__ __launch_bounds__(256) void chunk_combine(
    const unsigned short* __restrict__ Mb, const float* __restrict__ Dtot,
    unsigned short* __restrict__ SsT, float* __restrict__ Sfinal) {
  const int bid = blockIdx.x;
  const int vt = bid & 3, kt = (bid >> 2) & 3, bh = bid >> 4;
  const int k0 = kt * 32, v0 = vt * 32;
  const int tid = threadIdx.x;
  const int kk = tid >> 3, j0 = (tid & 7) * 4;
  const int vv = tid >> 3, k4 = (tid & 7) * 4;
  __shared__ unsigned short lt[32][36];
  float S[4] = {0.f, 0.f, 0.f, 0.f};
  for (int c = 0; c < NC; ++c) {
#pragma unroll
    for (int j = 0; j < 4; ++j) lt[j0 + j][kk] = f2bf(S[j]);
    __syncthreads();
    *(u16x4*)&SsT[((size_t)(bh * NC + c) * 128 + v0 + vv) * 128 + k0 + k4] =
        *(const u16x4*)&lt[vv][k4];
    const float d = Dtot[(bh * NC + c) * 128 + k0 + kk];
    const u16x4 m4 = *(const u16x4*)&Mb[((size_t)(bh * NC + c) * 128 + k0 + kk) * 128 + v0 + j0];
#pragma unroll
    for (int j = 0; j < 4; ++j) S[j] = fmaf(S[j], d, bf2f(m4[j]));
    __syncthreads();
  }
  float4 f; f.x = S[0]; f.y = S[1]; f.z = S[2]; f.w = S[3];
  *(float4*)&Sfinal[((size_t)bh * 128 + k0 + kk) * 128 + v0 + j0] = f;
}

// ---------------- Pass C: o += q~ @ S_c^T  (64-row tiles, 128 threads, RMW) -------------
__global__ __launch_bounds__(128) void gemm_inter(
    const unsigned short* __restrict__ Qt, const unsigned short* __restrict__ SsT,
    unsigned short* __restrict__ ylocal) {
  __shared__ unsigned short lAs[64 * 32];
  __shared__ unsigned short lBs[128 * 32];
  int bid = blockIdx.x;
  const int c = bid % NC, bh = bid / NC;
  const int b = bh >> 3, h = bh & 7;
  const int row0 = c * CH;
  const unsigned short* A = Qt + (size_t)(b * Lv + row0) * 1024 + h * 128;
  const unsigned short* Bt = SsT + (size_t)(bh * NC + c) * 16384;
  unsigned short* Y = ylocal + (size_t)(b * Lv + row0) * 1024 + h * 128;
  const int tid = threadIdx.x, wave = tid >> 6, lane = tid & 63;
  const int wn = wave << 6;
  f32x4 acc[4][4] = {};
  const int sr = lane >> 2, sc = (lane & 3) << 3;
  const int fr = lane & 15, fk = (lane >> 4) << 3;

  for (int k0 = 0; k0 < 128; k0 += 32) {
#pragma unroll
    for (int it = 0; it < 2; ++it) {
      const int rA = (wave * 2 + it) * 16 + sr;
      gld16(A + (size_t)rA * 1024 + k0 + sc, &lAs[(wave * 2 + it) * 512]);
    }
#pragma unroll
    for (int it = 0; it < 4; ++it) {
      const int rB = (wave * 4 + it) * 16 + sr;
      gld16(Bt + (size_t)rB * 128 + k0 + sc, &lBs[(wave * 4 + it) * 512]);
    }
    __syncthreads();
    bf16x8 af[4], bfr[4];
#pragma unroll
    for (int i = 0; i < 4; ++i) af[i] = *(const bf16x8*)&lAs[(i * 16 + fr) * 32 + fk];
#pragma unroll
    for (int j = 0; j < 4; ++j) bfr[j] = *(const bf16x8*)&lBs[(wn + j * 16 + fr) * 32 + fk];
#pragma unroll
    for (int i = 0; i < 4; ++i)
#pragma unroll
      for (int j = 0; j < 4; ++j)
        acc[i][j] = __builtin_amdgcn_mfma_f32_16x16x32_bf16(af[i], bfr[j], acc[i][j], 0, 0, 0);
    __syncthreads();
  }
  const int er = (lane >> 4) << 2, ec = lane & 15;
#pragma unroll
  for (int i = 0; i < 4; ++i)
#pragma unroll
    for (int j = 0; j < 4; ++j)
#pragma unroll
      for (int r = 0; r < 4; ++r) {
        const int m = i * 16 + er + r;
        const int n = wn + j * 16 + ec;
        const size_t idx = (size_t)m * 1024 + n;
        Y[idx] = f2bf(acc[i][j][r] + bf2f(Y[idx]));
      }
}

// ---------------- launch ----------------------------------------------------------------
extern "C" void kernel_launch(void* const* d_in, const int* in_sizes, int n_in,
                              void* d_out, int out_size, void* d_ws, size_t ws_size,
                              hipStream_t stream) {
  const float* x     = (const float*)d_in[0];
  const float* gamma = (const float*)d_in[1];
  const float* beta  = (const float*)d_in[2];
  const float* Wq    = (const float*)d_in[3];
  const float* Wk    = (const float*)d_in[4];
  const float* Wv    = (const float*)d_in[5];
  const float* Wg    = (const float*)d_in[6];
  const float* Wo    = (const float*)d_in[7];

  char* ws = (char*)d_ws;
  unsigned short* xnb  = (unsigned short*)(ws);
  unsigned short* C1   = (unsigned short*)(ws + 16777216);
  unsigned short* ybuf = (unsigned short*)(ws + 83886080);
  unsigned short* Wob  = (unsigned short*)(ws + 100663296);
  unsigned short* Wcat = (unsigned short*)(ws + 102760448);
  float*          Dtot = (float*)(ws + 111149056);
  unsigned short* Qt   = xnb;
  unsigned short* SsT  = C1;

  float* outp = (float*)d_out;
  float* Sout = outp + (size_t)BL * 1024;
  unsigned short* Mb = (unsigned short*)d_out;   // 32 MB == outp region exactly

  hipFuncSetAttribute((const void*)(gemm256<unsigned short, 256, 4096, true>),
                      hipFuncAttributeMaxDynamicSharedMemorySize, 131072);
  hipFuncSetAttribute((const void*)(gemm256<float, 128, 1024, false>),
                      hipFuncAttributeMaxDynamicSharedMemorySize, 98304);

  prep_kernel<<<dim3(8192 + 5120), dim3(256), 0, stream>>>(
      x, gamma, beta, xnb, Wq, Wk, Wv, Wg, Wo, Wcat, Wob);
  gemm256<unsigned short, 256, 4096, true><<<dim3(512), dim3(512), 131072, stream>>>(
      xnb, Wcat, C1);
  gla_chunk_mfma<<<dim3(32 * NC), dim3(256), 0, stream>>>(C1, ybuf, Qt, Mb, Dtot);
  chunk_combine<<<dim3(512), dim3(256), 0, stream>>>(Mb, Dtot, SsT, Sout);
  gemm_inter<<<dim3(32 * NC), dim3(128), 0, stream>>>(Qt, SsT, ybuf);
  gemm256<float, 128, 1024, false><<<dim3(256), dim3(512), 98304, stream>>>(
      ybuf, Wob, outp);
}

// Round 13
// 180.073 us; speedup vs baseline: 1.0950x; 1.0950x over previous
//
#include <hip/hip_runtime.h>

#define DEV static __device__ __forceinline__

typedef __bf16 bf16x8 __attribute__((ext_vector_type(8)));
typedef float f32x4 __attribute__((ext_vector_type(4)));
typedef unsigned short u16x8 __attribute__((ext_vector_type(8)));
typedef unsigned short u16x4 __attribute__((ext_vector_type(4)));
typedef unsigned int u32x2 __attribute__((ext_vector_type(2)));

constexpr int Bv = 4, Lv = 2048, Dv = 1024, Hv = 8;
constexpr int BL = Bv * Lv;   // 8192
constexpr int CH = 64;        // chunk length
constexpr int NC = Lv / CH;   // 32 chunks

DEV float bf2f(unsigned short u) {
  union { unsigned int i; float f; } c; c.i = ((unsigned int)u) << 16; return c.f;
}
DEV unsigned short f2bf(float f) {  // RNE
  union { float f; unsigned int i; } c; c.f = f;
  unsigned int x = c.i;
  unsigned int r = (x >> 16) & 1u;
  x += 0x7fffu + r;
  return (unsigned short)(x >> 16);
}

// packed f32x2 -> bf16x2 (low = a, high = b); no builtin on gfx950 -> asm (T12)
DEV unsigned int cvtpk(float a, float b) {
  unsigned int r;
  asm("v_cvt_pk_bf16_f32 %0, %1, %2" : "=v"(r) : "v"(a), "v"(b));
  return r;
}
DEV float frcp(float x) { float r; asm("v_rcp_f32 %0, %1" : "=v"(r) : "v"(x)); return r; }

// K=16 bf16 MFMA via asm. s_nop 1 guards VALU-write -> MFMA-read hazard.
DEV f32x4 mfma16(u32x2 a, u32x2 b, f32x4 c) {
  asm("s_nop 1\n\tv_mfma_f32_16x16x16_bf16 %0, %1, %2, %0" : "+v"(c) : "v"(a), "v"(b));
  return c;
}
DEV void mfma_fence() { asm volatile("s_nop 7\n\ts_nop 7"); }  // MFMA D -> VALU read

// ---------------- fused prep: LN rows (bid<8192) + weight cvt (bid>=8192) ---------------
__global__ __launch_bounds__(256) void prep_kernel(
    const float* __restrict__ x, const float* __restrict__ gamma,
    const float* __restrict__ beta, unsigned short* __restrict__ xnb,
    const float* __restrict__ Wq, const float* __restrict__ Wk,
    const float* __restrict__ Wv, const float* __restrict__ Wg,
    const float* __restrict__ Wo,
    unsigned short* __restrict__ Wcat, unsigned short* __restrict__ Wob) {
  const int bid = blockIdx.x, tid = threadIdx.x;
  if (bid < 8192) {
    const int row = bid;
    const float4 v = ((const float4*)(x + (size_t)row * 1024))[tid];
    float s = v.x + v.y + v.z + v.w;
    float q = v.x * v.x + v.y * v.y + v.z * v.z + v.w * v.w;
#pragma unroll
    for (int m = 1; m <= 32; m <<= 1) { s += __shfl_xor(s, m, 64); q += __shfl_xor(q, m, 64); }
    __shared__ float red[8];
    const int wave = tid >> 6, lane = tid & 63;
    if (lane == 0) { red[wave] = s; red[wave + 4] = q; }
    __syncthreads();
    s = red[0] + red[1] + red[2] + red[3];
    q = red[4] + red[5] + red[6] + red[7];
    const float mu = s * (1.0f / 1024.0f);
    const float var = q * (1.0f / 1024.0f) - mu * mu;
    const float rstd = rsqrtf(var + 1e-5f);
    const float4 g4 = ((const float4*)gamma)[tid];
    const float4 b4 = ((const float4*)beta)[tid];
    u16x4 o;
    o[0] = f2bf((v.x - mu) * rstd * g4.x + b4.x);
    o[1] = f2bf((v.y - mu) * rstd * g4.y + b4.y);
    o[2] = f2bf((v.z - mu) * rstd * g4.z + b4.z);
    o[3] = f2bf((v.w - mu) * rstd * g4.w + b4.w);
    ((u16x4*)(xnb + (size_t)row * 1024))[tid] = o;
  } else {
    const int i = (bid - 8192) * 256 + tid;
    const int NW4 = (4 * 1024 * 1024) / 4;
    const float* src; unsigned short* dst;
    if (i < NW4) {
      const int e0 = i * 4;
      const int which = e0 >> 20;
      const int off = e0 & ((1 << 20) - 1);
      src = (which == 0 ? Wq : which == 1 ? Wk : which == 2 ? Wv : Wg) + off;
      dst = Wcat + e0;
    } else {
      const int e0 = (i - NW4) * 4;
      src = Wo + e0;
      dst = Wob + e0;
    }
    const float4 v = *(const float4*)src;
    u16x4 o;
    o[0] = f2bf(v.x); o[1] = f2bf(v.y); o[2] = f2bf(v.z); o[3] = f2bf(v.w);
    *(u16x4*)dst = o;
  }
}

DEV void gld16(const void* g, void* l) {
  __builtin_amdgcn_global_load_lds((const __attribute__((address_space(1))) void*)g,
                                   (__attribute__((address_space(3))) void*)l, 16, 0, 0);
}

// ---------------- gemm256: 256xBN tile, BK=64, 8 waves, 1 barrier / K-tile --------------
// R11-best config (77.5 us measured). LDS: [buf2][A 32KB | B BN*128B], XOR-swizzled:
//   lds[row][chunk] = global[row][chunk ^ (row&7)]  (chunk = 16 B)
// linear gld16 dest + pre-swizzled global source; reads XOR the byte addr (rule 21).
// Double-buffered; one __syncthreads per K-tile (its vmcnt(0) drain = stage wait).
template <typename OUT_T, int BN, int NCOLS, bool GATE>
__global__ __launch_bounds__(512, 2) void gemm256(
    const unsigned short* __restrict__ A, const unsigned short* __restrict__ Bt,
    OUT_T* __restrict__ C) {
  constexpr int JW = BN / 64;             // j-frags per wave (4 or 2)
  constexpr int TN = NCOLS / BN;          // n tiles
  constexpr int BUFS = 16384 + BN * 64;   // shorts per buffer
  constexpr int KT = 16;                  // K = 1024 = 16 * 64
  extern __shared__ __align__(16) unsigned short lds[];
  int bid = blockIdx.x;
  const int cpx = gridDim.x >> 3;
  bid = (bid & 7) * cpx + (bid >> 3);     // XCD swizzle (grid % 8 == 0)
  const int tm = bid / TN, tn = bid % TN;
  const int gm = tm << 8, gn = tn * BN;
  const int tid = threadIdx.x, w = tid >> 6, l = tid & 63;
  const int wm = w >> 2, wn = w & 3;
  const int fr = l & 15, q = l >> 4;
  const int srow8 = l >> 3;                // stage: row within 8-row group
  const int scol = ((l & 7) ^ srow8) << 3; // stage: pre-swizzled source chunk
  const int kfirst = w & 1;                // ks-stagger parity
  const char* ldsc = (const char*)lds;

  f32x4 acc[8][JW] = {};

  const unsigned short* Abase = A + (size_t)(gm + srow8) * 1024 + scol;
  const unsigned short* Bbase = Bt + (size_t)(gn + srow8) * 1024 + scol;

  auto STAGE = [&](int buf, int kt, int ab, int hf) {
    const unsigned short* s0 = (ab == 0 ? Abase : Bbase) + (size_t)hf * 128 * 1024 + kt * 64;
    unsigned short* base = &lds[buf * BUFS + ab * 16384 + hf * 8192];
#pragma unroll
    for (int it = 0; it < 2; ++it)
      gld16(s0 + (size_t)(it * 8 + w) * 8192, base + (it * 8 + w) * 512);
  };
  auto RDA = [&](int buf, int i, int s) -> bf16x8 {
    const int byte = (i * 16 + fr) * 128 + ((s * 64 + q * 16) ^ ((fr & 7) << 4));
    return *(const bf16x8*)(ldsc + buf * (BUFS * 2) + wm * 16384 + byte);
  };
  auto RDB = [&](int buf, int j, int s) -> bf16x8 {
    const int byte = (wn * (JW * 16) + j * 16 + fr) * 128 +
                     ((s * 64 + q * 16) ^ ((fr & 7) << 4));
    return *(const bf16x8*)(ldsc + buf * (BUFS * 2) + 32768 + byte);
  };

  // prologue: stage K-tile 0 fully
  STAGE(0, 0, 0, 0); STAGE(0, 0, 0, 1);
#pragma unroll
  for (int hf = 0; hf < BN / 128; ++hf) STAGE(0, 0, 1, hf);
  __syncthreads();

  for (int kt = 0; kt < KT; ++kt) {
    const int buf = kt & 1;
    const bool st = kt + 1 < KT;
    bf16x8 a[8], b[JW];
#pragma unroll
    for (int s2 = 0; s2 < 2; ++s2) {
      const int ksel = kfirst ^ s2;   // odd waves take ks=1 first
#pragma unroll
      for (int i = 0; i < 8; ++i) a[i] = RDA(buf, i, ksel);
#pragma unroll
      for (int j = 0; j < JW; ++j) b[j] = RDB(buf, j, ksel);
      if (st) {
        if (s2 == 0) { STAGE(buf ^ 1, kt + 1, 0, 0); STAGE(buf ^ 1, kt + 1, 0, 1); }
        else {
#pragma unroll
          for (int hf = 0; hf < BN / 128; ++hf) STAGE(buf ^ 1, kt + 1, 1, hf);
        }
      }
      __builtin_amdgcn_s_setprio(1);
#pragma unroll
      for (int i = 0; i < 8; ++i)
#pragma unroll
        for (int j = 0; j < JW; ++j)
          acc[i][j] = __builtin_amdgcn_mfma_f32_16x16x32_bf16(a[i], b[j], acc[i][j], 0, 0, 0);
      __builtin_amdgcn_s_setprio(0);
    }
    __syncthreads();   // vmcnt(0)+lgkmcnt(0)+barrier: buf^1 staged, buf reads done
  }

  // epilogue: C row = m, col = n; optional sigmoid on gate cols
  const int er = q << 2, ec = fr;
#pragma unroll
  for (int i = 0; i < 8; ++i)
#pragma unroll
    for (int j = 0; j < JW; ++j)
#pragma unroll
      for (int r = 0; r < 4; ++r) {
        const int m = gm + wm * 128 + i * 16 + er + r;
        const int n = gn + wn * (JW * 16) + j * 16 + ec;
        float val = acc[i][j][r];
        if constexpr (GATE) { if (n >= 3072) val = 1.0f / (1.0f + __expf(-val)); }
        if constexpr (sizeof(OUT_T) == 2) ((unsigned short*)C)[(size_t)m * NCOLS + n] = f2bf(val);
        else                              C[(size_t)m * NCOLS + n] = val;
      }
}

// ---------------- Pass A: MFMA chunk kernel (CH=64, 4 sub-blocks of 16) -----------------
__global__ __launch_bounds__(256) void gla_chunk_mfma(
    const unsigned short* __restrict__ C1, unsigned short* __restrict__ ylocal,
    unsigned short* __restrict__ Qt, unsigned short* __restrict__ Mb,
    float* __restrict__ Dtot) {
  __shared__ unsigned short qs[16][136];   // q~  [t][k]
  __shared__ unsigned short ks[16][136];   // k~  [s][k]
  __shared__ unsigned short vt_[128][20];  // V^T [v][s]
  __shared__ unsigned short kh_[128][20];  // kh^T[k][s]
  __shared__ float lame[128];              // lam_end[k]

  const int bid = blockIdx.x;
  const int bh = bid >> 5, c = bid & 31;
  const int b = bh >> 3, h = bh & 7;
  const int tid = threadIdx.x, w = tid >> 6, l = tid & 63;
  const int tt = l & 15, sg = (l >> 4) << 2;
  const size_t row0 = (size_t)(b * Lv + c * CH);

  const float scale = 0.08838834764831845f;   // 128^-0.5
  const float inv_scale = 11.313708498984761f;

  f32x4 SA[8][2] = {};
  float chain = scale;

  for (int sb = 0; sb < 4; ++sb) {
    const size_t trow = row0 + sb * 16;
    if (tid < 128) {
      const int n = tid;
      const unsigned short* pc = C1 + trow * 4096 + h * 128 + n;
      float lam[16]; float lr = 1.f;
#pragma unroll
      for (int t = 0; t < 16; ++t) { lr *= bf2f(pc[(size_t)t * 4096 + 3072]); lam[t] = lr; }
      const float lend = lr;
      unsigned short khb[16];
#pragma unroll
      for (int t = 0; t < 16; ++t) {
        const float qv = bf2f(pc[(size_t)t * 4096]);
        const float kv = bf2f(pc[(size_t)t * 4096 + 1024]);
        const float qt = qv * lam[t];
        const float kt = kv * frcp(fmaxf(lam[t], 1e-30f));
        qs[t][n] = f2bf(qt);
        ks[t][n] = f2bf(kt);
        khb[t] = f2bf(kt * lend);
        Qt[(trow + t) * 1024 + h * 128 + n] = f2bf(qt * chain);
      }
#pragma unroll
      for (int s4 = 0; s4 < 16; s4 += 4)
        *(u16x4*)&kh_[n][s4] = *(u16x4*)&khb[s4];
      lame[n] = lend;
      chain *= lend;
    } else {
      const int i = tid - 128;
      const int s = i >> 3, vg = (i & 7) * 16;
      const unsigned short* pv = C1 + (trow + s) * 4096 + h * 128 + 2048 + vg;
      const u16x8 a0 = *(const u16x8*)pv;
      const u16x8 a1 = *(const u16x8*)(pv + 8);
#pragma unroll
      for (int e = 0; e < 8; ++e) { vt_[vg + e][s] = a0[e]; vt_[vg + 8 + e][s] = a1[e]; }
    }
    __syncthreads();

    f32x4 at = {};
#pragma unroll
    for (int k0 = 0; k0 < 128; k0 += 32) {
      const bf16x8 ka = *(const bf16x8*)&ks[tt][k0 + ((l >> 4) << 3)];
      const bf16x8 qa = *(const bf16x8*)&qs[tt][k0 + ((l >> 4) << 3)];
      at = __builtin_amdgcn_mfma_f32_16x16x32_bf16(ka, qa, at, 0, 0, 0);
    }
    float m0 = (sg + 0 <= tt) ? at[0] : 0.f;
    float m1 = (sg + 1 <= tt) ? at[1] : 0.f;
    float m2 = (sg + 2 <= tt) ? at[2] : 0.f;
    float m3 = (sg + 3 <= tt) ? at[3] : 0.f;
    u32x2 pf; pf[0] = cvtpk(m0, m1); pf[1] = cvtpk(m2, m3);

    u32x2 vf[2];
#pragma unroll
    for (int j = 0; j < 2; ++j)
      vf[j] = *(const u32x2*)&vt_[(w * 2 + j) * 16 + tt][sg];

    f32x4 OA[2] = {};
    if (sb) {
#pragma unroll
      for (int kt = 0; kt < 8; ++kt) {
        const u32x2 qf = *(const u32x2*)&qs[tt][kt * 16 + sg];
#pragma unroll
        for (int j = 0; j < 2; ++j) {
          u32x2 sa;
          sa[0] = cvtpk(SA[kt][j][0], SA[kt][j][1]);
          sa[1] = cvtpk(SA[kt][j][2], SA[kt][j][3]);
          OA[j] = mfma16(sa, qf, OA[j]);
        }
      }
    }
#pragma unroll
    for (int j = 0; j < 2; ++j) OA[j] = mfma16(vf[j], pf, OA[j]);
    mfma_fence();
#pragma unroll
    for (int j = 0; j < 2; ++j) {
      u16x4 yo;
#pragma unroll
      for (int r = 0; r < 4; ++r) yo[r] = f2bf(OA[j][r] * scale);
      *(u16x4*)&ylocal[(trow + tt) * 1024 + h * 128 + (w * 2 + j) * 16 + sg] = yo;
    }

#pragma unroll
    for (int kt = 0; kt < 8; ++kt) {
      const float4 lam4 = *(const float4*)&lame[kt * 16 + sg];
      const u32x2 khf = *(const u32x2*)&kh_[kt * 16 + tt][sg];
#pragma unroll
      for (int j = 0; j < 2; ++j) {
        f32x4 cs = SA[kt][j];
        cs[0] *= lam4.x; cs[1] *= lam4.y; cs[2] *= lam4.z; cs[3] *= lam4.w;
        SA[kt][j] = mfma16(khf, vf[j], cs);
      }
    }
    __syncthreads();
  }
  mfma_fence();

#pragma unroll
  for (int kt = 0; kt < 8; ++kt)
#pragma unroll
    for (int j = 0; j < 2; ++j)
#pragma unroll
      for (int r = 0; r < 4; ++r)
        Mb[((size_t)(bh * NC + c) * 128 + kt * 16 + sg + r) * 128 + (w * 2 + j) * 16 + tt] =
            f2bf(SA[kt][j][r]);
  if (tid < 128)
    Dtot[(bh * NC + c) * 128 + tid] = chain * inv_scale;
}

// ---------------- Pass B: serial chunk combine + transpose (1 barrier/chunk) ------------
__global__ __launch_bounds__(256) void chunk_combine(
    const unsigned short* __restrict__ Mb, const float* __restrict__ Dtot,
    unsigned short* __restrict__ SsT, float* __restrict__ Sfinal) {
  const int bid = blockIdx.x;
  const int vt = bid & 3, kt = (bid >> 2) & 3, bh = bid >> 4;
  const int k0 = kt * 32, v0 = vt * 32;
  const int tid = threadIdx.x;
  const int kk = tid >> 3, j0 = (tid & 7) * 4;
  const int vv = tid >> 3, k4 = (tid & 7) * 4;
  __shared__ unsigned short lt[2][32][36];   // double-buffered: 1 barrier per chunk
  float S[4] = {0.f, 0.f, 0.f, 0.f};
  for (int c = 0; c < NC; ++c) {
    const int pb = c & 1;
#pragma unroll
    for (int j = 0; j < 4; ++j) lt[pb][j0 + j][kk] = f2bf(S[j]);
    __syncthreads();
    *(u16x4*)&SsT[((size_t)(bh * NC + c) * 128 + v0 + vv) * 128 + k0 + k4] =
        *(const u16x4*)&lt[pb][vv][k4];
    const float d = Dtot[(bh * NC + c) * 128 + k0 + kk];
    const u16x4 m4 = *(const u16x4*)&Mb[((size_t)(bh * NC + c) * 128 + k0 + kk) * 128 + v0 + j0];
#pragma unroll
    for (int j = 0; j < 4; ++j) S[j] = fmaf(S[j], d, bf2f(m4[j]));
    // next iter writes lt[pb^1]; its last read was 2 iters ago, separated by this barrier
  }
  float4 f; f.x = S[0]; f.y = S[1]; f.z = S[2]; f.w = S[3];
  *(float4*)&Sfinal[((size_t)bh * 128 + k0 + kk) * 128 + v0 + j0] = f;
}

// ---------------- Pass C: o += q~ @ S_c^T  (stage-once, 256 thr, 1 barrier, RMW) --------
// Per block: one chunk (64 rows x 128 k) x SsT (128 v x 128 k). LDS chunk-swizzled:
// lds[row][chunk] = global[row][chunk ^ (row&7)] -> b128 frag reads conflict-free.
__global__ __launch_bounds__(256) void gemm_inter(
    const unsigned short* __restrict__ Qt, const unsigned short* __restrict__ SsT,
    unsigned short* __restrict__ ylocal) {
  __shared__ unsigned short lA[64 * 128];   // 16 KB, rows of 256B
  __shared__ unsigned short lB[128 * 128];  // 32 KB
  int bid = blockIdx.x;
  const int c = bid % NC, bh = bid / NC;
  const int b = bh >> 3, h = bh & 7;
  const int row0 = c * CH;
  const unsigned short* A = Qt + (size_t)(b * Lv + row0) * 1024 + h * 128;
  const unsigned short* Bt = SsT + (size_t)(bh * NC + c) * 16384;
  unsigned short* Y = ylocal + (size_t)(b * Lv + row0) * 1024 + h * 128;
  const int tid = threadIdx.x, w = tid >> 6, l = tid & 63;
  const int fr = l & 15, q = l >> 4;
  const int srw = l >> 4;                  // row within 4-row call group

  // stage A (16 wave-calls) + B (32 wave-calls); wave w takes calls w, w+4, ...
#pragma unroll
  for (int it = 0; it < 4; ++it) {
    const int call = it * 4 + w;
    const int row = call * 4 + srw;
    const int sc = (l & 15) ^ (row & 7);
    gld16(A + (size_t)row * 1024 + sc * 8, &lA[call * 512]);
  }
#pragma unroll
  for (int it = 0; it < 8; ++it) {
    const int call = it * 4 + w;
    const int row = call * 4 + srw;
    const int sc = (l & 15) ^ (row & 7);
    gld16(Bt + (size_t)row * 128 + sc * 8, &lB[call * 512]);
  }
  __syncthreads();   // vmcnt(0) drain: everything staged

  f32x4 acc[4][2] = {};
  const char* lac = (const char*)lA;
  const char* lbc = (const char*)lB;
#pragma unroll
  for (int ks = 0; ks < 4; ++ks) {
    bf16x8 a[4], bb[2];
#pragma unroll
    for (int i = 0; i < 4; ++i) {
      const int row = i * 16 + fr;
      const int phys = (ks * 4 + q) ^ (row & 7);
      a[i] = *(const bf16x8*)(lac + row * 256 + phys * 16);
    }
#pragma unroll
    for (int j = 0; j < 2; ++j) {
      const int row = w * 32 + j * 16 + fr;
      const int phys = (ks * 4 + q) ^ (row & 7);
      bb[j] = *(const bf16x8*)(lbc + row * 256 + phys * 16);
    }
#pragma unroll
    for (int i = 0; i < 4; ++i)
#pragma unroll
      for (int j = 0; j < 2; ++j)
        acc[i][j] = __builtin_amdgcn_mfma_f32_16x16x32_bf16(a[i], bb[j], acc[i][j], 0, 0, 0);
  }
  const int er = q << 2, ec = fr;
#pragma unroll
  for (int i = 0; i < 4; ++i)
#pragma unroll
    for (int j = 0; j < 2; ++j)
#pragma unroll
      for (int r = 0; r < 4; ++r) {
        const int m = i * 16 + er + r;
        const int n = w * 32 + j * 16 + ec;
        const size_t idx = (size_t)m * 1024 + n;
        Y[idx] = f2bf(acc[i][j][r] + bf2f(Y[idx]));
      }
}

// ---------------- launch ----------------------------------------------------------------
extern "C" void kernel_launch(void* const* d_in, const int* in_sizes, int n_in,
                              void* d_out, int out_size, void* d_ws, size_t ws_size,
                              hipStream_t stream) {
  const float* x     = (const float*)d_in[0];
  const float* gamma = (const float*)d_in[1];
  const float* beta  = (const float*)d_in[2];
  const float* Wq    = (const float*)d_in[3];
  const float* Wk    = (const float*)d_in[4];
  const float* Wv    = (const float*)d_in[5];
  const float* Wg    = (const float*)d_in[6];
  const float* Wo    = (const float*)d_in[7];

  char* ws = (char*)d_ws;
  unsigned short* xnb  = (unsigned short*)(ws);
  unsigned short* C1   = (unsigned short*)(ws + 16777216);
  unsigned short* ybuf = (unsigned short*)(ws + 83886080);
  unsigned short* Wob  = (unsigned short*)(ws + 100663296);
  unsigned short* Wcat = (unsigned short*)(ws + 102760448);
  float*          Dtot = (float*)(ws + 111149056);
  unsigned short* Qt   = xnb;
  unsigned short* SsT  = C1;

  float* outp = (float*)d_out;
  float* Sout = outp + (size_t)BL * 1024;
  unsigned short* Mb = (unsigned short*)d_out;   // 32 MB == outp region exactly

  hipFuncSetAttribute((const void*)(gemm256<unsigned short, 256, 4096, true>),
                      hipFuncAttributeMaxDynamicSharedMemorySize, 131072);
  hipFuncSetAttribute((const void*)(gemm256<float, 128, 1024, false>),
                      hipFuncAttributeMaxDynamicSharedMemorySize, 98304);

  prep_kernel<<<dim3(8192 + 5120), dim3(256), 0, stream>>>(
      x, gamma, beta, xnb, Wq, Wk, Wv, Wg, Wo, Wcat, Wob);
  gemm256<unsigned short, 256, 4096, true><<<dim3(512), dim3(512), 131072, stream>>>(
      xnb, Wcat, C1);
  gla_chunk_mfma<<<dim3(32 * NC), dim3(256), 0, stream>>>(C1, ybuf, Qt, Mb, Dtot);
  chunk_combine<<<dim3(512), dim3(256), 0, stream>>>(Mb, Dtot, SsT, Sout);
  gemm_inter<<<dim3(32 * NC), dim3(256), 0, stream>>>(Qt, SsT, ybuf);
  gemm256<float, 128, 1024, false><<<dim3(256), dim3(512), 98304, stream>>>(
      ybuf, Wob, outp);
}

// Round 15
// 178.472 us; speedup vs baseline: 1.1048x; 1.0090x over previous
//
#include <hip/hip_runtime.h>

#define DEV static __device__ __forceinline__

typedef __bf16 bf16x8 __attribute__((ext_vector_type(8)));
typedef float f32x4 __attribute__((ext_vector_type(4)));
typedef unsigned short u16x8 __attribute__((ext_vector_type(8)));
typedef unsigned short u16x4 __attribute__((ext_vector_type(4)));
typedef unsigned int u32x2 __attribute__((ext_vector_type(2)));

constexpr int Bv = 4, Lv = 2048, Dv = 1024, Hv = 8;
constexpr int BL = Bv * Lv;   // 8192
constexpr int CH = 64;        // chunk length
constexpr int NC = Lv / CH;   // 32 chunks

DEV float bf2f(unsigned short u) {
  union { unsigned int i; float f; } c; c.i = ((unsigned int)u) << 16; return c.f;
}
DEV unsigned short f2bf(float f) {  // RNE
  union { float f; unsigned int i; } c; c.f = f;
  unsigned int x = c.i;
  unsigned int r = (x >> 16) & 1u;
  x += 0x7fffu + r;
  return (unsigned short)(x >> 16);
}

// packed f32x2 -> bf16x2 (low = a, high = b); no builtin on gfx950 -> asm (T12)
DEV unsigned int cvtpk(float a, float b) {
  unsigned int r;
  asm("v_cvt_pk_bf16_f32 %0, %1, %2" : "=v"(r) : "v"(a), "v"(b));
  return r;
}
DEV float frcp(float x) { float r; asm("v_rcp_f32 %0, %1" : "=v"(r) : "v"(x)); return r; }

// K=16 bf16 MFMA via asm. s_nop 1 guards VALU-write -> MFMA-read hazard.
DEV f32x4 mfma16(u32x2 a, u32x2 b, f32x4 c) {
  asm("s_nop 1\n\tv_mfma_f32_16x16x16_bf16 %0, %1, %2, %0" : "+v"(c) : "v"(a), "v"(b));
  return c;
}
DEV void mfma_fence() { asm volatile("s_nop 7\n\ts_nop 7"); }  // MFMA D -> VALU read

// ---------------- fused prep: LN rows (bid<8192) + weight cvt (bid>=8192) ---------------
__global__ __launch_bounds__(256) void prep_kernel(
    const float* __restrict__ x, const float* __restrict__ gamma,
    const float* __restrict__ beta, unsigned short* __restrict__ xnb,
    const float* __restrict__ Wq, const float* __restrict__ Wk,
    const float* __restrict__ Wv, const float* __restrict__ Wg,
    const float* __restrict__ Wo,
    unsigned short* __restrict__ Wcat, unsigned short* __restrict__ Wob) {
  const int bid = blockIdx.x, tid = threadIdx.x;
  if (bid < 8192) {
    const int row = bid;
    const float4 v = ((const float4*)(x + (size_t)row * 1024))[tid];
    float s = v.x + v.y + v.z + v.w;
    float q = v.x * v.x + v.y * v.y + v.z * v.z + v.w * v.w;
#pragma unroll
    for (int m = 1; m <= 32; m <<= 1) { s += __shfl_xor(s, m, 64); q += __shfl_xor(q, m, 64); }
    __shared__ float red[8];
    const int wave = tid >> 6, lane = tid & 63;
    if (lane == 0) { red[wave] = s; red[wave + 4] = q; }
    __syncthreads();
    s = red[0] + red[1] + red[2] + red[3];
    q = red[4] + red[5] + red[6] + red[7];
    const float mu = s * (1.0f / 1024.0f);
    const float var = q * (1.0f / 1024.0f) - mu * mu;
    const float rstd = rsqrtf(var + 1e-5f);
    const float4 g4 = ((const float4*)gamma)[tid];
    const float4 b4 = ((const float4*)beta)[tid];
    u16x4 o;
    o[0] = f2bf((v.x - mu) * rstd * g4.x + b4.x);
    o[1] = f2bf((v.y - mu) * rstd * g4.y + b4.y);
    o[2] = f2bf((v.z - mu) * rstd * g4.z + b4.z);
    o[3] = f2bf((v.w - mu) * rstd * g4.w + b4.w);
    ((u16x4*)(xnb + (size_t)row * 1024))[tid] = o;
  } else {
    const int i = (bid - 8192) * 256 + tid;
    const int NW4 = (4 * 1024 * 1024) / 4;
    const float* src; unsigned short* dst;
    if (i < NW4) {
      const int e0 = i * 4;
      const int which = e0 >> 20;
      const int off = e0 & ((1 << 20) - 1);
      src = (which == 0 ? Wq : which == 1 ? Wk : which == 2 ? Wv : Wg) + off;
      dst = Wcat + e0;
    } else {
      const int e0 = (i - NW4) * 4;
      src = Wo + e0;
      dst = Wob + e0;
    }
    const float4 v = *(const float4*)src;
    u16x4 o;
    o[0] = f2bf(v.x); o[1] = f2bf(v.y); o[2] = f2bf(v.z); o[3] = f2bf(v.w);
    *(u16x4*)dst = o;
  }
}

DEV void gld16(const void* g, void* l) {
  __builtin_amdgcn_global_load_lds((const __attribute__((address_space(1))) void*)g,
                                   (__attribute__((address_space(3))) void*)l, 16, 0, 0);
}

// ---------------- gemm256: 256xBN tile, BK=64, 8 waves, 1 barrier / K-tile --------------
// R11-best config (77.5 us measured). LDS: [buf2][A 32KB | B BN*128B], XOR-swizzled:
//   lds[row][chunk] = global[row][chunk ^ (row&7)]  (chunk = 16 B)
// linear gld16 dest + pre-swizzled global source; reads XOR the byte addr (rule 21).
// Double-buffered; one __syncthreads per K-tile (its vmcnt(0) drain = stage wait).
template <typename OUT_T, int BN, int NCOLS, bool GATE>
__global__ __launch_bounds__(512, 2) void gemm256(
    const unsigned short* __restrict__ A, const unsigned short* __restrict__ Bt,
    OUT_T* __restrict__ C) {
  constexpr int JW = BN / 64;             // j-frags per wave (4 or 2)
  constexpr int TN = NCOLS / BN;          // n tiles
  constexpr int BUFS = 16384 + BN * 64;   // shorts per buffer
  constexpr int KT = 16;                  // K = 1024 = 16 * 64
  extern __shared__ __align__(16) unsigned short lds[];
  int bid = blockIdx.x;
  const int cpx = gridDim.x >> 3;
  bid = (bid & 7) * cpx + (bid >> 3);     // XCD swizzle (grid % 8 == 0)
  const int tm = bid / TN, tn = bid % TN;
  const int gm = tm << 8, gn = tn * BN;
  const int tid = threadIdx.x, w = tid >> 6, l = tid & 63;
  const int wm = w >> 2, wn = w & 3;
  const int fr = l & 15, q = l >> 4;
  const int srow8 = l >> 3;                // stage: row within 8-row group
  const int scol = ((l & 7) ^ srow8) << 3; // stage: pre-swizzled source chunk
  const int kfirst = w & 1;                // ks-stagger parity
  const char* ldsc = (const char*)lds;

  f32x4 acc[8][JW] = {};

  const unsigned short* Abase = A + (size_t)(gm + srow8) * 1024 + scol;
  const unsigned short* Bbase = Bt + (size_t)(gn + srow8) * 1024 + scol;

  auto STAGE = [&](int buf, int kt, int ab, int hf) {
    const unsigned short* s0 = (ab == 0 ? Abase : Bbase) + (size_t)hf * 128 * 1024 + kt * 64;
    unsigned short* base = &lds[buf * BUFS + ab * 16384 + hf * 8192];
#pragma unroll
    for (int it = 0; it < 2; ++it)
      gld16(s0 + (size_t)(it * 8 + w) * 8192, base + (it * 8 + w) * 512);
  };
  auto RDA = [&](int buf, int i, int s) -> bf16x8 {
    const int byte = (i * 16 + fr) * 128 + ((s * 64 + q * 16) ^ ((fr & 7) << 4));
    return *(const bf16x8*)(ldsc + buf * (BUFS * 2) + wm * 16384 + byte);
  };
  auto RDB = [&](int buf, int j, int s) -> bf16x8 {
    const int byte = (wn * (JW * 16) + j * 16 + fr) * 128 +
                     ((s * 64 + q * 16) ^ ((fr & 7) << 4));
    return *(const bf16x8*)(ldsc + buf * (BUFS * 2) + 32768 + byte);
  };

  // prologue: stage K-tile 0 fully
  STAGE(0, 0, 0, 0); STAGE(0, 0, 0, 1);
#pragma unroll
  for (int hf = 0; hf < BN / 128; ++hf) STAGE(0, 0, 1, hf);
  __syncthreads();

  for (int kt = 0; kt < KT; ++kt) {
    const int buf = kt & 1;
    const bool st = kt + 1 < KT;
    bf16x8 a[8], b[JW];
#pragma unroll
    for (int s2 = 0; s2 < 2; ++s2) {
      const int ksel = kfirst ^ s2;   // odd waves take ks=1 first
#pragma unroll
      for (int i = 0; i < 8; ++i) a[i] = RDA(buf, i, ksel);
#pragma unroll
      for (int j = 0; j < JW; ++j) b[j] = RDB(buf, j, ksel);
      if (st) {
        if (s2 == 0) { STAGE(buf ^ 1, kt + 1, 0, 0); STAGE(buf ^ 1, kt + 1, 0, 1); }
        else {
#pragma unroll
          for (int hf = 0; hf < BN / 128; ++hf) STAGE(buf ^ 1, kt + 1, 1, hf);
        }
      }
      __builtin_amdgcn_s_setprio(1);
#pragma unroll
      for (int i = 0; i < 8; ++i)
#pragma unroll
        for (int j = 0; j < JW; ++j)
          acc[i][j] = __builtin_amdgcn_mfma_f32_16x16x32_bf16(a[i], b[j], acc[i][j], 0, 0, 0);
      __builtin_amdgcn_s_setprio(0);
    }
    __syncthreads();   // vmcnt(0)+lgkmcnt(0)+barrier: buf^1 staged, buf reads done
  }

  // epilogue: C row = m, col = n; optional sigmoid on gate cols
  const int er = q << 2, ec = fr;
#pragma unroll
  for (int i = 0; i < 8; ++i)
#pragma unroll
    for (int j = 0; j < JW; ++j)
#pragma unroll
      for (int r = 0; r < 4; ++r) {
        const int m = gm + wm * 128 + i * 16 + er + r;
        const int n = gn + wn * (JW * 16) + j * 16 + ec;
        float val = acc[i][j][r];
        if constexpr (GATE) { if (n >= 3072) val = 1.0f / (1.0f + __expf(-val)); }
        if constexpr (sizeof(OUT_T) == 2) ((unsigned short*)C)[(size_t)m * NCOLS + n] = f2bf(val);
        else                              C[(size_t)m * NCOLS + n] = val;
      }
}

// ---------------- gemm128: 128x128 tile, BK=64, 4 waves, 64KB LDS -> 2 blocks/CU --------
// Final projection (M=8192, N=1024, K=1024, fp32 out). Cross-block overlap at barriers
// (2 blocks/CU). Staging FIXED vs R14: gld16's LDS dest is WAVE-uniform + lane*16 (m104)
// -> each wave-call stages its OWN 8-row/1024B slice (dest depends on w), lane l covers
// local row l>>3, pre-swizzled source chunk (l&7)^(l>>3). 16 wave-calls per operand.
__global__ __launch_bounds__(256, 2) void gemm128(
    const unsigned short* __restrict__ A, const unsigned short* __restrict__ Bt,
    float* __restrict__ C) {
  constexpr int TN = 8;                    // 1024 / 128
  constexpr int BUFS = 2 * 128 * 64;       // shorts per buffer (A 16KB + B 16KB)
  constexpr int KT = 16;
  extern __shared__ __align__(16) unsigned short lds[];
  int bid = blockIdx.x;
  const int cpx = gridDim.x >> 3;
  bid = (bid & 7) * cpx + (bid >> 3);      // XCD swizzle (512 % 8 == 0)
  const int tm = bid / TN, tn = bid % TN;
  const int gm = tm << 7, gn = tn << 7;
  const int tid = threadIdx.x, w = tid >> 6, l = tid & 63;
  const int wm = w >> 1, wn = w & 1;
  const int fr = l & 15, q = l >> 4;
  const int kfirst = w & 1;
  const int lr = l >> 3;                   // stage: local row within 8-row wave slice
  const int sc8 = (l & 7) ^ lr;            // stage: pre-swizzled source chunk
  const char* ldsc = (const char*)lds;

  f32x4 acc[4][4] = {};

  const unsigned short* Abase = A + (size_t)(gm + lr) * 1024 + sc8 * 8;
  const unsigned short* Bbase = Bt + (size_t)(gn + lr) * 1024 + sc8 * 8;

  auto STAGE = [&](int buf, int kt, int ab) {   // full 128x64 operand = 16 wave-calls
    const unsigned short* s0 = (ab == 0 ? Abase : Bbase) + kt * 64;
    unsigned short* base = &lds[buf * BUFS + ab * 8192];
#pragma unroll
    for (int it = 0; it < 4; ++it)
      gld16(s0 + (size_t)((it * 4 + w) * 8) * 1024, base + (it * 4 + w) * 512);
  };
  auto RDA = [&](int buf, int i, int s) -> bf16x8 {
    const int row = wm * 64 + i * 16 + fr;
    const int byte = row * 128 + ((s * 64 + q * 16) ^ ((row & 7) << 4));
    return *(const bf16x8*)(ldsc + buf * (BUFS * 2) + byte);
  };
  auto RDB = [&](int buf, int j, int s) -> bf16x8 {
    const int row = wn * 64 + j * 16 + fr;
    const int byte = row * 128 + ((s * 64 + q * 16) ^ ((row & 7) << 4));
    return *(const bf16x8*)(ldsc + buf * (BUFS * 2) + 16384 + byte);
  };

  STAGE(0, 0, 0); STAGE(0, 0, 1);
  __syncthreads();

  for (int kt = 0; kt < KT; ++kt) {
    const int buf = kt & 1;
    const bool st = kt + 1 < KT;
    bf16x8 a[4], b[4];
#pragma unroll
    for (int s2 = 0; s2 < 2; ++s2) {
      const int ksel = kfirst ^ s2;
#pragma unroll
      for (int i = 0; i < 4; ++i) a[i] = RDA(buf, i, ksel);
#pragma unroll
      for (int j = 0; j < 4; ++j) b[j] = RDB(buf, j, ksel);
      if (st) STAGE(buf ^ 1, kt + 1, s2);   // s2=0: A, s2=1: B
      __builtin_amdgcn_s_setprio(1);
#pragma unroll
      for (int i = 0; i < 4; ++i)
#pragma unroll
        for (int j = 0; j < 4; ++j)
          acc[i][j] = __builtin_amdgcn_mfma_f32_16x16x32_bf16(a[i], b[j], acc[i][j], 0, 0, 0);
      __builtin_amdgcn_s_setprio(0);
    }
    __syncthreads();
  }

  const int er = q << 2, ec = fr;
#pragma unroll
  for (int i = 0; i < 4; ++i)
#pragma unroll
    for (int j = 0; j < 4; ++j)
#pragma unroll
      for (int r = 0; r < 4; ++r) {
        const int m = gm + wm * 64 + i * 16 + er + r;
        const int n = gn + wn * 64 + j * 16 + ec;
        C[(size_t)m * 1024 + n] = acc[i][j][r];
      }
}

// ---------------- Pass A: MFMA chunk kernel (CH=64, 4 sub-blocks of 16) -----------------
__global__ __launch_bounds__(256) void gla_chunk_mfma(
    const unsigned short* __restrict__ C1, unsigned short* __restrict__ ylocal,
    unsigned short* __restrict__ Qt, unsigned short* __restrict__ Mb,
    float* __restrict__ Dtot) {
  __shared__ unsigned short qs[16][136];   // q~  [t][k]
  __shared__ unsigned short ks[16][136];   // k~  [s][k]
  __shared__ unsigned short vt_[128][20];  // V^T [v][s]
  __shared__ unsigned short kh_[128][20];  // kh^T[k][s]
  __shared__ float lame[128];              // lam_end[k]

  const int bid = blockIdx.x;
  const int bh = bid >> 5, c = bid & 31;
  const int b = bh >> 3, h = bh & 7;
  const int tid = threadIdx.x, w = tid >> 6, l = tid & 63;
  const int tt = l & 15, sg = (l >> 4) << 2;
  const size_t row0 = (size_t)(b * Lv + c * CH);

  const float scale = 0.08838834764831845f;   // 128^-0.5
  const float inv_scale = 11.313708498984761f;

  f32x4 SA[8][2] = {};
  float chain = scale;

  for (int sb = 0; sb < 4; ++sb) {
    const size_t trow = row0 + sb * 16;
    if (tid < 128) {
      const int n = tid;
      const unsigned short* pc = C1 + trow * 4096 + h * 128 + n;
      float lam[16]; float lr = 1.f;
#pragma unroll
      for (int t = 0; t < 16; ++t) { lr *= bf2f(pc[(size_t)t * 4096 + 3072]); lam[t] = lr; }
      const float lend = lr;
      unsigned short khb[16];
#pragma unroll
      for (int t = 0; t < 16; ++t) {
        const float qv = bf2f(pc[(size_t)t * 4096]);
        const float kv = bf2f(pc[(size_t)t * 4096 + 1024]);
        const float qt = qv * lam[t];
        const float kt = kv * frcp(fmaxf(lam[t], 1e-30f));
        qs[t][n] = f2bf(qt);
        ks[t][n] = f2bf(kt);
        khb[t] = f2bf(kt * lend);
        Qt[(trow + t) * 1024 + h * 128 + n] = f2bf(qt * chain);
      }
#pragma unroll
      for (int s4 = 0; s4 < 16; s4 += 4)
        *(u16x4*)&kh_[n][s4] = *(u16x4*)&khb[s4];
      lame[n] = lend;
      chain *= lend;
    } else {
      const int i = tid - 128;
      const int s = i >> 3, vg = (i & 7) * 16;
      const unsigned short* pv = C1 + (trow + s) * 4096 + h * 128 + 2048 + vg;
      const u16x8 a0 = *(const u16x8*)pv;
      const u16x8 a1 = *(const u16x8*)(pv + 8);
#pragma unroll
      for (int e = 0; e < 8; ++e) { vt_[vg + e][s] = a0[e]; vt_[vg + 8 + e][s] = a1[e]; }
    }
    __syncthreads();

    f32x4 at = {};
#pragma unroll
    for (int k0 = 0; k0 < 128; k0 += 32) {
      const bf16x8 ka = *(const bf16x8*)&ks[tt][k0 + ((l >> 4) << 3)];
      const bf16x8 qa = *(const bf16x8*)&qs[tt][k0 + ((l >> 4) << 3)];
      at = __builtin_amdgcn_mfma_f32_16x16x32_bf16(ka, qa, at, 0, 0, 0);
    }
    float m0 = (sg + 0 <= tt) ? at[0] : 0.f;
    float m1 = (sg + 1 <= tt) ? at[1] : 0.f;
    float m2 = (sg + 2 <= tt) ? at[2] : 0.f;
    float m3 = (sg + 3 <= tt) ? at[3] : 0.f;
    u32x2 pf; pf[0] = cvtpk(m0, m1); pf[1] = cvtpk(m2, m3);

    u32x2 vf[2];
#pragma unroll
    for (int j = 0; j < 2; ++j)
      vf[j] = *(const u32x2*)&vt_[(w * 2 + j) * 16 + tt][sg];

    f32x4 OA[2] = {};
    if (sb) {
#pragma unroll
      for (int kt = 0; kt < 8; ++kt) {
        const u32x2 qf = *(const u32x2*)&qs[tt][kt * 16 + sg];
#pragma unroll
        for (int j = 0; j < 2; ++j) {
          u32x2 sa;
          sa[0] = cvtpk(SA[kt][j][0], SA[kt][j][1]);
          sa[1] = cvtpk(SA[kt][j][2], SA[kt][j][3]);
          OA[j] = mfma16(sa, qf, OA[j]);
        }
      }
    }
#pragma unroll
    for (int j = 0; j < 2; ++j) OA[j] = mfma16(vf[j], pf, OA[j]);
    mfma_fence();
#pragma unroll
    for (int j = 0; j < 2; ++j) {
      u16x4 yo;
#pragma unroll
      for (int r = 0; r < 4; ++r) yo[r] = f2bf(OA[j][r] * scale);
      *(u16x4*)&ylocal[(trow + tt) * 1024 + h * 128 + (w * 2 + j) * 16 + sg] = yo;
    }

#pragma unroll
    for (int kt = 0; kt < 8; ++kt) {
      const float4 lam4 = *(const float4*)&lame[kt * 16 + sg];
      const u32x2 khf = *(const u32x2*)&kh_[kt * 16 + tt][sg];
#pragma unroll
      for (int j = 0; j < 2; ++j) {
        f32x4 cs = SA[kt][j];
        cs[0] *= lam4.x; cs[1] *= lam4.y; cs[2] *= lam4.z; cs[3] *= lam4.w;
        SA[kt][j] = mfma16(khf, vf[j], cs);
      }
    }
    __syncthreads();
  }
  mfma_fence();

#pragma unroll
  for (int kt = 0; kt < 8; ++kt)
#pragma unroll
    for (int j = 0; j < 2; ++j)
#pragma unroll
      for (int r = 0; r < 4; ++r)
        Mb[((size_t)(bh * NC + c) * 128 + kt * 16 + sg + r) * 128 + (w * 2 + j) * 16 + tt] =
            f2bf(SA[kt][j][r]);
  if (tid < 128)
    Dtot[(bh * NC + c) * 128 + tid] = chain * inv_scale;
}

// ---------------- Pass B: serial chunk combine + transpose (1 barrier/chunk) ------------
__global__ __launch_bounds__(256) void chunk_combine(
    const unsigned short* __restrict__ Mb, const float* __restrict__ Dtot,
    unsigned short* __restrict__ SsT, float* __restrict__ Sfinal) {
  const int bid = blockIdx.x;
  const int vt = bid & 3, kt = (bid >> 2) & 3, bh = bid >> 4;
  const int k0 = kt * 32, v0 = vt * 32;
  const int tid = threadIdx.x;
  const int kk = tid >> 3, j0 = (tid & 7) * 4;
  const int vv = tid >> 3, k4 = (tid & 7) * 4;
  __shared__ unsigned short lt[2][32][36];   // double-buffered: 1 barrier per chunk
  float S[4] = {0.f, 0.f, 0.f, 0.f};
  for (int c = 0; c < NC; ++c) {
    const int pb = c & 1;
#pragma unroll
    for (int j = 0; j < 4; ++j) lt[pb][j0 + j][kk] = f2bf(S[j]);
    __syncthreads();
    *(u16x4*)&SsT[((size_t)(bh * NC + c) * 128 + v0 + vv) * 128 + k0 + k4] =
        *(const u16x4*)&lt[pb][vv][k4];
    const float d = Dtot[(bh * NC + c) * 128 + k0 + kk];
    const u16x4 m4 = *(const u16x4*)&Mb[((size_t)(bh * NC + c) * 128 + k0 + kk) * 128 + v0 + j0];
#pragma unroll
    for (int j = 0; j < 4; ++j) S[j] = fmaf(S[j], d, bf2f(m4[j]));
  }
  float4 f; f.x = S[0]; f.y = S[1]; f.z = S[2]; f.w = S[3];
  *(float4*)&Sfinal[((size_t)bh * 128 + k0 + kk) * 128 + v0 + j0] = f;
}

// ---------------- Pass C: o += q~ @ S_c^T  (stage-once, 256 thr, 1 barrier, RMW) --------
__global__ __launch_bounds__(256) void gemm_inter(
    const unsigned short* __restrict__ Qt, const unsigned short* __restrict__ SsT,
    unsigned short* __restrict__ ylocal) {
  __shared__ unsigned short lA[64 * 128];   // 16 KB, rows of 256B
  __shared__ unsigned short lB[128 * 128];  // 32 KB
  int bid = blockIdx.x;
  const int c = bid % NC, bh = bid / NC;
  const int b = bh >> 3, h = bh & 7;
  const int row0 = c * CH;
  const unsigned short* A = Qt + (size_t)(b * Lv + row0) * 1024 + h * 128;
  const unsigned short* Bt = SsT + (size_t)(bh * NC + c) * 16384;
  unsigned short* Y = ylocal + (size_t)(b * Lv + row0) * 1024 + h * 128;
  const int tid = threadIdx.x, w = tid >> 6, l = tid & 63;
  const int fr = l & 15, q = l >> 4;
  const int srw = l >> 4;                  // row within 4-row call group

#pragma unroll
  for (int it = 0; it < 4; ++it) {
    const int call = it * 4 + w;
    const int row = call * 4 + srw;
    const int sc = (l & 15) ^ (row & 7);
    gld16(A + (size_t)row * 1024 + sc * 8, &lA[call * 512]);
  }
#pragma unroll
  for (int it = 0; it < 8; ++it) {
    const int call = it * 4 + w;
    const int row = call * 4 + srw;
    const int sc = (l & 15) ^ (row & 7);
    gld16(Bt + (size_t)row * 128 + sc * 8, &lB[call * 512]);
  }
  __syncthreads();   // vmcnt(0) drain: everything staged

  f32x4 acc[4][2] = {};
  const char* lac = (const char*)lA;
  const char* lbc = (const char*)lB;
#pragma unroll
  for (int ks = 0; ks < 4; ++ks) {
    bf16x8 a[4], bb[2];
#pragma unroll
    for (int i = 0; i < 4; ++i) {
      const int row = i * 16 + fr;
      const int phys = (ks * 4 + q) ^ (row & 7);
      a[i] = *(const bf16x8*)(lac + row * 256 + phys * 16);
    }
#pragma unroll
    for (int j = 0; j < 2; ++j) {
      const int row = w * 32 + j * 16 + fr;
      const int phys = (ks * 4 + q) ^ (row & 7);
      bb[j] = *(const bf16x8*)(lbc + row * 256 + phys * 16);
    }
#pragma unroll
    for (int i = 0; i < 4; ++i)
#pragma unroll
      for (int j = 0; j < 2; ++j)
        acc[i][j] = __builtin_amdgcn_mfma_f32_16x16x32_bf16(a[i], bb[j], acc[i][j], 0, 0, 0);
  }
  const int er = q << 2, ec = fr;
#pragma unroll
  for (int i = 0; i < 4; ++i)
#pragma unroll
    for (int j = 0; j < 2; ++j)
#pragma unroll
      for (int r = 0; r < 4; ++r) {
        const int m = i * 16 + er + r;
        const int n = w * 32 + j * 16 + ec;
        const size_t idx = (size_t)m * 1024 + n;
        Y[idx] = f2bf(acc[i][j][r] + bf2f(Y[idx]));
      }
}

// ---------------- launch ----------------------------------------------------------------
extern "C" void kernel_launch(void* const* d_in, const int* in_sizes, int n_in,
                              void* d_out, int out_size, void* d_ws, size_t ws_size,
                              hipStream_t stream) {
  const float* x     = (const float*)d_in[0];
  const float* gamma = (const float*)d_in[1];
  const float* beta  = (const float*)d_in[2];
  const float* Wq    = (const float*)d_in[3];
  const float* Wk    = (const float*)d_in[4];
  const float* Wv    = (const float*)d_in[5];
  const float* Wg    = (const float*)d_in[6];
  const float* Wo    = (const float*)d_in[7];

  char* ws = (char*)d_ws;
  unsigned short* xnb  = (unsigned short*)(ws);
  unsigned short* C1   = (unsigned short*)(ws + 16777216);
  unsigned short* ybuf = (unsigned short*)(ws + 83886080);
  unsigned short* Wob  = (unsigned short*)(ws + 100663296);
  unsigned short* Wcat = (unsigned short*)(ws + 102760448);
  float*          Dtot = (float*)(ws + 111149056);
  unsigned short* Qt   = xnb;
  unsigned short* SsT  = C1;

  float* outp = (float*)d_out;
  float* Sout = outp + (size_t)BL * 1024;
  unsigned short* Mb = (unsigned short*)d_out;   // 32 MB == outp region exactly

  hipFuncSetAttribute((const void*)(gemm256<unsigned short, 256, 4096, true>),
                      hipFuncAttributeMaxDynamicSharedMemorySize, 131072);
  hipFuncSetAttribute((const void*)gemm128,
                      hipFuncAttributeMaxDynamicSharedMemorySize, 65536);

  prep_kernel<<<dim3(8192 + 5120), dim3(256), 0, stream>>>(
      x, gamma, beta, xnb, Wq, Wk, Wv, Wg, Wo, Wcat, Wob);
  gemm256<unsigned short, 256, 4096, true><<<dim3(512), dim3(512), 131072, stream>>>(
      xnb, Wcat, C1);
  gla_chunk_mfma<<<dim3(32 * NC), dim3(256), 0, stream>>>(C1, ybuf, Qt, Mb, Dtot);
  chunk_combine<<<dim3(512), dim3(256), 0, stream>>>(Mb, Dtot, SsT, Sout);
  gemm_inter<<<dim3(32 * NC), dim3(256), 0, stream>>>(Qt, SsT, ybuf);
  gemm128<<<dim3(512), dim3(256), 65536, stream>>>(ybuf, Wob, outp);
}

// Round 16
// 177.523 us; speedup vs baseline: 1.1107x; 1.0053x over previous
//
#include <hip/hip_runtime.h>

#define DEV static __device__ __forceinline__

typedef __bf16 bf16x8 __attribute__((ext_vector_type(8)));
typedef float f32x4 __attribute__((ext_vector_type(4)));
typedef unsigned short u16x8 __attribute__((ext_vector_type(8)));
typedef unsigned short u16x4 __attribute__((ext_vector_type(4)));
typedef unsigned int u32x2 __attribute__((ext_vector_type(2)));

constexpr int Bv = 4, Lv = 2048, Dv = 1024, Hv = 8;
constexpr int BL = Bv * Lv;   // 8192
constexpr int CH = 64;        // chunk length
constexpr int NC = Lv / CH;   // 32 chunks

DEV float bf2f(unsigned short u) {
  union { unsigned int i; float f; } c; c.i = ((unsigned int)u) << 16; return c.f;
}
DEV unsigned short f2bf(float f) {  // RNE
  union { float f; unsigned int i; } c; c.f = f;
  unsigned int x = c.i;
  unsigned int r = (x >> 16) & 1u;
  x += 0x7fffu + r;
  return (unsigned short)(x >> 16);
}

// packed f32x2 -> bf16x2 (low = a, high = b); no builtin on gfx950 -> asm (T12)
DEV unsigned int cvtpk(float a, float b) {
  unsigned int r;
  asm("v_cvt_pk_bf16_f32 %0, %1, %2" : "=v"(r) : "v"(a), "v"(b));
  return r;
}
DEV float frcp(float x) { float r; asm("v_rcp_f32 %0, %1" : "=v"(r) : "v"(x)); return r; }

// K=16 bf16 MFMA via asm. s_nop 1 guards VALU-write -> MFMA-read hazard.
DEV f32x4 mfma16(u32x2 a, u32x2 b, f32x4 c) {
  asm("s_nop 1\n\tv_mfma_f32_16x16x16_bf16 %0, %1, %2, %0" : "+v"(c) : "v"(a), "v"(b));
  return c;
}
DEV void mfma_fence() { asm volatile("s_nop 7\n\ts_nop 7"); }  // MFMA D -> VALU read

// ---------------- fused prep: LN rows (bid<2048, wave-per-row) + weight cvt -------------
__global__ __launch_bounds__(256) void prep_kernel(
    const float* __restrict__ x, const float* __restrict__ gamma,
    const float* __restrict__ beta, unsigned short* __restrict__ xnb,
    const float* __restrict__ Wq, const float* __restrict__ Wk,
    const float* __restrict__ Wv, const float* __restrict__ Wg,
    const float* __restrict__ Wo,
    unsigned short* __restrict__ Wcat, unsigned short* __restrict__ Wob) {
  const int bid = blockIdx.x, tid = threadIdx.x;
  if (bid < 2048) {
    // ---- LayerNorm: one wave per row (no LDS, no barrier) ----
    const int wave = tid >> 6, lane = tid & 63;
    const int row = bid * 4 + wave;
    const float* xr = x + (size_t)row * 1024;
    float4 v[4];
#pragma unroll
    for (int i = 0; i < 4; ++i) v[i] = ((const float4*)xr)[i * 64 + lane];
    float s = 0.f, q = 0.f;
#pragma unroll
    for (int i = 0; i < 4; ++i) {
      s += v[i].x + v[i].y + v[i].z + v[i].w;
      q += v[i].x * v[i].x + v[i].y * v[i].y + v[i].z * v[i].z + v[i].w * v[i].w;
    }
#pragma unroll
    for (int m = 1; m <= 32; m <<= 1) { s += __shfl_xor(s, m, 64); q += __shfl_xor(q, m, 64); }
    const float mu = s * (1.0f / 1024.0f);
    const float var = q * (1.0f / 1024.0f) - mu * mu;
    const float rstd = rsqrtf(var + 1e-5f);
#pragma unroll
    for (int i = 0; i < 4; ++i) {
      const float4 g4 = ((const float4*)gamma)[i * 64 + lane];
      const float4 b4 = ((const float4*)beta)[i * 64 + lane];
      u16x4 o;
      o[0] = f2bf((v[i].x - mu) * rstd * g4.x + b4.x);
      o[1] = f2bf((v[i].y - mu) * rstd * g4.y + b4.y);
      o[2] = f2bf((v[i].z - mu) * rstd * g4.z + b4.z);
      o[3] = f2bf((v[i].w - mu) * rstd * g4.w + b4.w);
      ((u16x4*)(xnb + (size_t)row * 1024))[i * 64 + lane] = o;
    }
  } else {
    // ---- weight conversion ----
    const int i = (bid - 2048) * 256 + tid;
    const int NW4 = (4 * 1024 * 1024) / 4;
    const float* src; unsigned short* dst;
    if (i < NW4) {
      const int e0 = i * 4;
      const int which = e0 >> 20;
      const int off = e0 & ((1 << 20) - 1);
      src = (which == 0 ? Wq : which == 1 ? Wk : which == 2 ? Wv : Wg) + off;
      dst = Wcat + e0;
    } else {
      const int e0 = (i - NW4) * 4;
      src = Wo + e0;
      dst = Wob + e0;
    }
    const float4 v = *(const float4*)src;
    u16x4 o;
    o[0] = f2bf(v.x); o[1] = f2bf(v.y); o[2] = f2bf(v.z); o[3] = f2bf(v.w);
    *(u16x4*)dst = o;
  }
}

DEV void gld16(const void* g, void* l) {
  __builtin_amdgcn_global_load_lds((const __attribute__((address_space(1))) void*)g,
                                   (__attribute__((address_space(3))) void*)l, 16, 0, 0);
}

// ---------------- gemm256: 256xBN tile, BK=64, 8 waves, 1 barrier / K-tile --------------
// R11-best config (77.5 us measured). LDS: [buf2][A 32KB | B BN*128B], XOR-swizzled:
//   lds[row][chunk] = global[row][chunk ^ (row&7)]  (chunk = 16 B)
// linear gld16 dest + pre-swizzled global source; reads XOR the byte addr (rule 21).
// Double-buffered; one __syncthreads per K-tile (its vmcnt(0) drain = stage wait).
template <typename OUT_T, int BN, int NCOLS, bool GATE>
__global__ __launch_bounds__(512, 2) void gemm256(
    const unsigned short* __restrict__ A, const unsigned short* __restrict__ Bt,
    OUT_T* __restrict__ C) {
  constexpr int JW = BN / 64;             // j-frags per wave (4 or 2)
  constexpr int TN = NCOLS / BN;          // n tiles
  constexpr int BUFS = 16384 + BN * 64;   // shorts per buffer
  constexpr int KT = 16;                  // K = 1024 = 16 * 64
  extern __shared__ __align__(16) unsigned short lds[];
  int bid = blockIdx.x;
  const int cpx = gridDim.x >> 3;
  bid = (bid & 7) * cpx + (bid >> 3);     // XCD swizzle (grid % 8 == 0)
  const int tm = bid / TN, tn = bid % TN;
  const int gm = tm << 8, gn = tn * BN;
  const int tid = threadIdx.x, w = tid >> 6, l = tid & 63;
  const int wm = w >> 2, wn = w & 3;
  const int fr = l & 15, q = l >> 4;
  const int srow8 = l >> 3;                // stage: row within 8-row group
  const int scol = ((l & 7) ^ srow8) << 3; // stage: pre-swizzled source chunk
  const int kfirst = w & 1;                // ks-stagger parity
  const char* ldsc = (const char*)lds;

  f32x4 acc[8][JW] = {};

  const unsigned short* Abase = A + (size_t)(gm + srow8) * 1024 + scol;
  const unsigned short* Bbase = Bt + (size_t)(gn + srow8) * 1024 + scol;

  auto STAGE = [&](int buf, int kt, int ab, int hf) {
    const unsigned short* s0 = (ab == 0 ? Abase : Bbase) + (size_t)hf * 128 * 1024 + kt * 64;
    unsigned short* base = &lds[buf * BUFS + ab * 16384 + hf * 8192];
#pragma unroll
    for (int it = 0; it < 2; ++it)
      gld16(s0 + (size_t)(it * 8 + w) * 8192, base + (it * 8 + w) * 512);
  };
  auto RDA = [&](int buf, int i, int s) -> bf16x8 {
    const int byte = (i * 16 + fr) * 128 + ((s * 64 + q * 16) ^ ((fr & 7) << 4));
    return *(const bf16x8*)(ldsc + buf * (BUFS * 2) + wm * 16384 + byte);
  };
  auto RDB = [&](int buf, int j, int s) -> bf16x8 {
    const int byte = (wn * (JW * 16) + j * 16 + fr) * 128 +
                     ((s * 64 + q * 16) ^ ((fr & 7) << 4));
    return *(const bf16x8*)(ldsc + buf * (BUFS * 2) + 32768 + byte);
  };

  // prologue: stage K-tile 0 fully
  STAGE(0, 0, 0, 0); STAGE(0, 0, 0, 1);
#pragma unroll
  for (int hf = 0; hf < BN / 128; ++hf) STAGE(0, 0, 1, hf);
  __syncthreads();

  for (int kt = 0; kt < KT; ++kt) {
    const int buf = kt & 1;
    const bool st = kt + 1 < KT;
    bf16x8 a[8], b[JW];
#pragma unroll
    for (int s2 = 0; s2 < 2; ++s2) {
      const int ksel = kfirst ^ s2;   // odd waves take ks=1 first
#pragma unroll
      for (int i = 0; i < 8; ++i) a[i] = RDA(buf, i, ksel);
#pragma unroll
      for (int j = 0; j < JW; ++j) b[j] = RDB(buf, j, ksel);
      if (st) {
        if (s2 == 0) { STAGE(buf ^ 1, kt + 1, 0, 0); STAGE(buf ^ 1, kt + 1, 0, 1); }
        else {
#pragma unroll
          for (int hf = 0; hf < BN / 128; ++hf) STAGE(buf ^ 1, kt + 1, 1, hf);
        }
      }
      __builtin_amdgcn_s_setprio(1);
#pragma unroll
      for (int i = 0; i < 8; ++i)
#pragma unroll
        for (int j = 0; j < JW; ++j)
          acc[i][j] = __builtin_amdgcn_mfma_f32_16x16x32_bf16(a[i], b[j], acc[i][j], 0, 0, 0);
      __builtin_amdgcn_s_setprio(0);
    }
    __syncthreads();   // vmcnt(0)+lgkmcnt(0)+barrier: buf^1 staged, buf reads done
  }

  // epilogue: C row = m, col = n; optional sigmoid on gate cols
  const int er = q << 2, ec = fr;
#pragma unroll
  for (int i = 0; i < 8; ++i)
#pragma unroll
    for (int j = 0; j < JW; ++j)
#pragma unroll
      for (int r = 0; r < 4; ++r) {
        const int m = gm + wm * 128 + i * 16 + er + r;
        const int n = gn + wn * (JW * 16) + j * 16 + ec;
        float val = acc[i][j][r];
        if constexpr (GATE) { if (n >= 3072) val = 1.0f / (1.0f + __expf(-val)); }
        if constexpr (sizeof(OUT_T) == 2) ((unsigned short*)C)[(size_t)m * NCOLS + n] = f2bf(val);
        else                              C[(size_t)m * NCOLS + n] = val;
      }
}

// ---------------- gemm128: 128x128 tile, BK=64, 4 waves, 64KB LDS -> 2 blocks/CU --------
// Final projection (M=8192, N=1024, K=1024, fp32 out). Cross-block overlap at barriers
// (2 blocks/CU). gld16's LDS dest is WAVE-uniform + lane*16 (m104) -> each wave-call
// stages its OWN 8-row/1024B slice; lane l covers local row l>>3, source chunk (l&7)^(l>>3).
__global__ __launch_bounds__(256, 2) void gemm128(
    const unsigned short* __restrict__ A, const unsigned short* __restrict__ Bt,
    float* __restrict__ C) {
  constexpr int TN = 8;                    // 1024 / 128
  constexpr int BUFS = 2 * 128 * 64;       // shorts per buffer (A 16KB + B 16KB)
  constexpr int KT = 16;
  extern __shared__ __align__(16) unsigned short lds[];
  int bid = blockIdx.x;
  const int cpx = gridDim.x >> 3;
  bid = (bid & 7) * cpx + (bid >> 3);      // XCD swizzle (512 % 8 == 0)
  const int tm = bid / TN, tn = bid % TN;
  const int gm = tm << 7, gn = tn << 7;
  const int tid = threadIdx.x, w = tid >> 6, l = tid & 63;
  const int wm = w >> 1, wn = w & 1;
  const int fr = l & 15, q = l >> 4;
  const int kfirst = w & 1;
  const int lr = l >> 3;                   // stage: local row within 8-row wave slice
  const int sc8 = (l & 7) ^ lr;            // stage: pre-swizzled source chunk
  const char* ldsc = (const char*)lds;

  f32x4 acc[4][4] = {};

  const unsigned short* Abase = A + (size_t)(gm + lr) * 1024 + sc8 * 8;
  const unsigned short* Bbase = Bt + (size_t)(gn + lr) * 1024 + sc8 * 8;

  auto STAGE = [&](int buf, int kt, int ab) {   // full 128x64 operand = 16 wave-calls
    const unsigned short* s0 = (ab == 0 ? Abase : Bbase) + kt * 64;
    unsigned short* base = &lds[buf * BUFS + ab * 8192];
#pragma unroll
    for (int it = 0; it < 4; ++it)
      gld16(s0 + (size_t)((it * 4 + w) * 8) * 1024, base + (it * 4 + w) * 512);
  };
  auto RDA = [&](int buf, int i, int s) -> bf16x8 {
    const int row = wm * 64 + i * 16 + fr;
    const int byte = row * 128 + ((s * 64 + q * 16) ^ ((row & 7) << 4));
    return *(const bf16x8*)(ldsc + buf * (BUFS * 2) + byte);
  };
  auto RDB = [&](int buf, int j, int s) -> bf16x8 {
    const int row = wn * 64 + j * 16 + fr;
    const int byte = row * 128 + ((s * 64 + q * 16) ^ ((row & 7) << 4));
    return *(const bf16x8*)(ldsc + buf * (BUFS * 2) + 16384 + byte);
  };

  STAGE(0, 0, 0); STAGE(0, 0, 1);
  __syncthreads();

  for (int kt = 0; kt < KT; ++kt) {
    const int buf = kt & 1;
    const bool st = kt + 1 < KT;
    bf16x8 a[4], b[4];
#pragma unroll
    for (int s2 = 0; s2 < 2; ++s2) {
      const int ksel = kfirst ^ s2;
#pragma unroll
      for (int i = 0; i < 4; ++i) a[i] = RDA(buf, i, ksel);
#pragma unroll
      for (int j = 0; j < 4; ++j) b[j] = RDB(buf, j, ksel);
      if (st) STAGE(buf ^ 1, kt + 1, s2);   // s2=0: A, s2=1: B
      __builtin_amdgcn_s_setprio(1);
#pragma unroll
      for (int i = 0; i < 4; ++i)
#pragma unroll
        for (int j = 0; j < 4; ++j)
          acc[i][j] = __builtin_amdgcn_mfma_f32_16x16x32_bf16(a[i], b[j], acc[i][j], 0, 0, 0);
      __builtin_amdgcn_s_setprio(0);
    }
    __syncthreads();
  }

  const int er = q << 2, ec = fr;
#pragma unroll
  for (int i = 0; i < 4; ++i)
#pragma unroll
    for (int j = 0; j < 4; ++j)
#pragma unroll
      for (int r = 0; r < 4; ++r) {
        const int m = gm + wm * 64 + i * 16 + er + r;
        const int n = gn + wn * 64 + j * 16 + ec;
        C[(size_t)m * 1024 + n] = acc[i][j][r];
      }
}

// ---------------- Pass A: MFMA chunk kernel (CH=64, 4 sub-blocks of 16) -----------------
__global__ __launch_bounds__(256) void gla_chunk_mfma(
    const unsigned short* __restrict__ C1, unsigned short* __restrict__ ylocal,
    unsigned short* __restrict__ Qt, unsigned short* __restrict__ Mb,
    float* __restrict__ Dtot) {
  __shared__ unsigned short qs[16][136];   // q~  [t][k]
  __shared__ unsigned short ks[16][136];   // k~  [s][k]
  __shared__ unsigned short vt_[128][20];  // V^T [v][s]
  __shared__ unsigned short kh_[128][20];  // kh^T[k][s]
  __shared__ float lame[128];              // lam_end[k]

  const int bid = blockIdx.x;
  const int bh = bid >> 5, c = bid & 31;
  const int b = bh >> 3, h = bh & 7;
  const int tid = threadIdx.x, w = tid >> 6, l = tid & 63;
  const int tt = l & 15, sg = (l >> 4) << 2;
  const size_t row0 = (size_t)(b * Lv + c * CH);

  const float scale = 0.08838834764831845f;   // 128^-0.5
  const float inv_scale = 11.313708498984761f;

  f32x4 SA[8][2] = {};
  float chain = scale;

  for (int sb = 0; sb < 4; ++sb) {
    const size_t trow = row0 + sb * 16;
    if (tid < 128) {
      const int n = tid;
      const unsigned short* pc = C1 + trow * 4096 + h * 128 + n;
      float lam[16]; float lr = 1.f;
#pragma unroll
      for (int t = 0; t < 16; ++t) { lr *= bf2f(pc[(size_t)t * 4096 + 3072]); lam[t] = lr; }
      const float lend = lr;
      unsigned short khb[16];
#pragma unroll
      for (int t = 0; t < 16; ++t) {
        const float qv = bf2f(pc[(size_t)t * 4096]);
        const float kv = bf2f(pc[(size_t)t * 4096 + 1024]);
        const float qt = qv * lam[t];
        const float kt = kv * frcp(fmaxf(lam[t], 1e-30f));
        qs[t][n] = f2bf(qt);
        ks[t][n] = f2bf(kt);
        khb[t] = f2bf(kt * lend);
        Qt[(trow + t) * 1024 + h * 128 + n] = f2bf(qt * chain);
      }
#pragma unroll
      for (int s4 = 0; s4 < 16; s4 += 4)
        *(u16x4*)&kh_[n][s4] = *(u16x4*)&khb[s4];
      lame[n] = lend;
      chain *= lend;
    } else {
      const int i = tid - 128;
      const int s = i >> 3, vg = (i & 7) * 16;
      const unsigned short* pv = C1 + (trow + s) * 4096 + h * 128 + 2048 + vg;
      const u16x8 a0 = *(const u16x8*)pv;
      const u16x8 a1 = *(const u16x8*)(pv + 8);
#pragma unroll
      for (int e = 0; e < 8; ++e) { vt_[vg + e][s] = a0[e]; vt_[vg + 8 + e][s] = a1[e]; }
    }
    __syncthreads();

    f32x4 at = {};
#pragma unroll
    for (int k0 = 0; k0 < 128; k0 += 32) {
      const bf16x8 ka = *(const bf16x8*)&ks[tt][k0 + ((l >> 4) << 3)];
      const bf16x8 qa = *(const bf16x8*)&qs[tt][k0 + ((l >> 4) << 3)];
      at = __builtin_amdgcn_mfma_f32_16x16x32_bf16(ka, qa, at, 0, 0, 0);
    }
    float m0 = (sg + 0 <= tt) ? at[0] : 0.f;
    float m1 = (sg + 1 <= tt) ? at[1] : 0.f;
    float m2 = (sg + 2 <= tt) ? at[2] : 0.f;
    float m3 = (sg + 3 <= tt) ? at[3] : 0.f;
    u32x2 pf; pf[0] = cvtpk(m0, m1); pf[1] = cvtpk(m2, m3);

    u32x2 vf[2];
#pragma unroll
    for (int j = 0; j < 2; ++j)
      vf[j] = *(const u32x2*)&vt_[(w * 2 + j) * 16 + tt][sg];

    f32x4 OA[2] = {};
    if (sb) {
#pragma unroll
      for (int kt = 0; kt < 8; ++kt) {
        const u32x2 qf = *(const u32x2*)&qs[tt][kt * 16 + sg];
#pragma unroll
        for (int j = 0; j < 2; ++j) {
          u32x2 sa;
          sa[0] = cvtpk(SA[kt][j][0], SA[kt][j][1]);
          sa[1] = cvtpk(SA[kt][j][2], SA[kt][j][3]);
          OA[j] = mfma16(sa, qf, OA[j]);
        }
      }
    }
#pragma unroll
    for (int j = 0; j < 2; ++j) OA[j] = mfma16(vf[j], pf, OA[j]);
    mfma_fence();
#pragma unroll
    for (int j = 0; j < 2; ++j) {
      u16x4 yo;
#pragma unroll
      for (int r = 0; r < 4; ++r) yo[r] = f2bf(OA[j][r] * scale);
      *(u16x4*)&ylocal[(trow + tt) * 1024 + h * 128 + (w * 2 + j) * 16 + sg] = yo;
    }

#pragma unroll
    for (int kt = 0; kt < 8; ++kt) {
      const float4 lam4 = *(const float4*)&lame[kt * 16 + sg];
      const u32x2 khf = *(const u32x2*)&kh_[kt * 16 + tt][sg];
#pragma unroll
      for (int j = 0; j < 2; ++j) {
        f32x4 cs = SA[kt][j];
        cs[0] *= lam4.x; cs[1] *= lam4.y; cs[2] *= lam4.z; cs[3] *= lam4.w;
        SA[kt][j] = mfma16(khf, vf[j], cs);
      }
    }
    __syncthreads();
  }
  mfma_fence();

#pragma unroll
  for (int kt = 0; kt < 8; ++kt)
#pragma unroll
    for (int j = 0; j < 2; ++j)
#pragma unroll
      for (int r = 0; r < 4; ++r)
        Mb[((size_t)(bh * NC + c) * 128 + kt * 16 + sg + r) * 128 + (w * 2 + j) * 16 + tt] =
            f2bf(SA[kt][j][r]);
  if (tid < 128)
    Dtot[(bh * NC + c) * 128 + tid] = chain * inv_scale;
}

// ---------------- Pass B: serial chunk combine + transpose (1 barrier/chunk) ------------
__global__ __launch_bounds__(256) void chunk_combine(
    const unsigned short* __restrict__ Mb, const float* __restrict__ Dtot,
    unsigned short* __restrict__ SsT, float* __restrict__ Sfinal) {
  const int bid = blockIdx.x;
  const int vt = bid & 3, kt = (bid >> 2) & 3, bh = bid >> 4;
  const int k0 = kt * 32, v0 = vt * 32;
  const int tid = threadIdx.x;
  const int kk = tid >> 3, j0 = (tid & 7) * 4;
  const int vv = tid >> 3, k4 = (tid & 7) * 4;
  __shared__ unsigned short lt[2][32][36];   // double-buffered: 1 barrier per chunk
  float S[4] = {0.f, 0.f, 0.f, 0.f};
  for (int c = 0; c < NC; ++c) {
    const int pb = c & 1;
#pragma unroll
    for (int j = 0; j < 4; ++j) lt[pb][j0 + j][kk] = f2bf(S[j]);
    __syncthreads();
    *(u16x4*)&SsT[((size_t)(bh * NC + c) * 128 + v0 + vv) * 128 + k0 + k4] =
        *(const u16x4*)&lt[pb][vv][k4];
    const float d = Dtot[(bh * NC + c) * 128 + k0 + kk];
    const u16x4 m4 = *(const u16x4*)&Mb[((size_t)(bh * NC + c) * 128 + k0 + kk) * 128 + v0 + j0];
#pragma unroll
    for (int j = 0; j < 4; ++j) S[j] = fmaf(S[j], d, bf2f(m4[j]));
  }
  float4 f; f.x = S[0]; f.y = S[1]; f.z = S[2]; f.w = S[3];
  *(float4*)&Sfinal[((size_t)bh * 128 + k0 + kk) * 128 + v0 + j0] = f;
}

// ---------------- Pass C: o += q~ @ S_c^T  (stage-once, 256 thr, 1 barrier, RMW) --------
__global__ __launch_bounds__(256) void gemm_inter(
    const unsigned short* __restrict__ Qt, const unsigned short* __restrict__ SsT,
    unsigned short* __restrict__ ylocal) {
  __shared__ unsigned short lA[64 * 128];   // 16 KB, rows of 256B
  __shared__ unsigned short lB[128 * 128];  // 32 KB
  int bid = blockIdx.x;
  const int c = bid % NC, bh = bid / NC;
  const int b = bh >> 3, h = bh & 7;
  const int row0 = c * CH;
  const unsigned short* A = Qt + (size_t)(b * Lv + row0) * 1024 + h * 128;
  const unsigned short* Bt = SsT + (size_t)(bh * NC + c) * 16384;
  unsigned short* Y = ylocal + (size_t)(b * Lv + row0) * 1024 + h * 128;
  const int tid = threadIdx.x, w = tid >> 6, l = tid & 63;
  const int fr = l & 15, q = l >> 4;
  const int srw = l >> 4;                  // row within 4-row call group

#pragma unroll
  for (int it = 0; it < 4; ++it) {
    const int call = it * 4 + w;
    const int row = call * 4 + srw;
    const int sc = (l & 15) ^ (row & 7);
    gld16(A + (size_t)row * 1024 + sc * 8, &lA[call * 512]);
  }
#pragma unroll
  for (int it = 0; it < 8; ++it) {
    const int call = it * 4 + w;
    const int row = call * 4 + srw;
    const int sc = (l & 15) ^ (row & 7);
    gld16(Bt + (size_t)row * 128 + sc * 8, &lB[call * 512]);
  }
  __syncthreads();   // vmcnt(0) drain: everything staged

  f32x4 acc[4][2] = {};
  const char* lac = (const char*)lA;
  const char* lbc = (const char*)lB;
#pragma unroll
  for (int ks = 0; ks < 4; ++ks) {
    bf16x8 a[4], bb[2];
#pragma unroll
    for (int i = 0; i < 4; ++i) {
      const int row = i * 16 + fr;
      const int phys = (ks * 4 + q) ^ (row & 7);
      a[i] = *(const bf16x8*)(lac + row * 256 + phys * 16);
    }
#pragma unroll
    for (int j = 0; j < 2; ++j) {
      const int row = w * 32 + j * 16 + fr;
      const int phys = (ks * 4 + q) ^ (row & 7);
      bb[j] = *(const bf16x8*)(lbc + row * 256 + phys * 16);
    }
#pragma unroll
    for (int i = 0; i < 4; ++i)
#pragma unroll
      for (int j = 0; j < 2; ++j)
        acc[i][j] = __builtin_amdgcn_mfma_f32_16x16x32_bf16(a[i], bb[j], acc[i][j], 0, 0, 0);
  }
  const int er = q << 2, ec = fr;
#pragma unroll
  for (int i = 0; i < 4; ++i)
#pragma unroll
    for (int j = 0; j < 2; ++j)
#pragma unroll
      for (int r = 0; r < 4; ++r) {
        const int m = i * 16 + er + r;
        const int n = w * 32 + j * 16 + ec;
        const size_t idx = (size_t)m * 1024 + n;
        Y[idx] = f2bf(acc[i][j][r] + bf2f(Y[idx]));
      }
}

// ---------------- launch ----------------------------------------------------------------
extern "C" void kernel_launch(void* const* d_in, const int* in_sizes, int n_in,
                              void* d_out, int out_size, void* d_ws, size_t ws_size,
                              hipStream_t stream) {
  const float* x     = (const float*)d_in[0];
  const float* gamma = (const float*)d_in[1];
  const float* beta  = (const float*)d_in[2];
  const float* Wq    = (const float*)d_in[3];
  const float* Wk    = (const float*)d_in[4];
  const float* Wv    = (const float*)d_in[5];
  const float* Wg    = (const float*)d_in[6];
  const float* Wo    = (const float*)d_in[7];

  char* ws = (char*)d_ws;
  unsigned short* xnb  = (unsigned short*)(ws);
  unsigned short* C1   = (unsigned short*)(ws + 16777216);
  unsigned short* ybuf = (unsigned short*)(ws + 83886080);
  unsigned short* Wob  = (unsigned short*)(ws + 100663296);
  unsigned short* Wcat = (unsigned short*)(ws + 102760448);
  float*          Dtot = (float*)(ws + 111149056);
  unsigned short* Qt   = xnb;
  unsigned short* SsT  = C1;

  float* outp = (float*)d_out;
  float* Sout = outp + (size_t)BL * 1024;
  unsigned short* Mb = (unsigned short*)d_out;   // 32 MB == outp region exactly

  hipFuncSetAttribute((const void*)(gemm256<unsigned short, 256, 4096, true>),
                      hipFuncAttributeMaxDynamicSharedMemorySize, 131072);
  hipFuncSetAttribute((const void*)gemm128,
                      hipFuncAttributeMaxDynamicSharedMemorySize, 65536);

  prep_kernel<<<dim3(2048 + 5120), dim3(256), 0, stream>>>(
      x, gamma, beta, xnb, Wq, Wk, Wv, Wg, Wo, Wcat, Wob);
  gemm256<unsigned short, 256, 4096, true><<<dim3(512), dim3(512), 131072, stream>>>(
      xnb, Wcat, C1);
  gla_chunk_mfma<<<dim3(32 * NC), dim3(256), 0, stream>>>(C1, ybuf, Qt, Mb, Dtot);
  chunk_combine<<<dim3(512), dim3(256), 0, stream>>>(Mb, Dtot, SsT, Sout);
  gemm_inter<<<dim3(32 * NC), dim3(256), 0, stream>>>(Qt, SsT, ybuf);
  gemm128<<<dim3(512), dim3(256), 65536, stream>>>(ybuf, Wob, outp);
}